// Round 7
// baseline (745.705 us; speedup 1.0000x reference)
//
#include <hip/hip_runtime.h>
#include <math.h>

#define BB 512
#define SS 100
#define HH 768

typedef __bf16 bf16x8 __attribute__((ext_vector_type(8)));
typedef __bf16 bf16x4 __attribute__((ext_vector_type(4)));
typedef float f32x4 __attribute__((ext_vector_type(4)));
typedef float f32x16 __attribute__((ext_vector_type(16)));

__device__ __forceinline__ void gld16(const void* g, void* l) {
    __builtin_amdgcn_global_load_lds((const __attribute__((address_space(1))) char*)g,
                                     (__attribute__((address_space(3))) char*)l, 16, 0, 0);
}

// ---------------- K0: d_rep[b,h] = mean_s X[b,s,h]  (coalesced float4 col-reduce) ----------------
__global__ __launch_bounds__(256) void k_drep(const float* __restrict__ X,
                                              float* __restrict__ drep) {
    int b = blockIdx.x, g = blockIdx.y;
    int lane = threadIdx.x & 63, w = threadIdx.x >> 6;
    const float4* xb = (const float4*)(X + (size_t)b * SS * HH);
    int c4 = g * 64 + lane;
    float4 s = {0.f, 0.f, 0.f, 0.f};
    for (int r = w; r < SS; r += 4) {
        float4 v = xb[r * 192 + c4];
        s.x += v.x; s.y += v.y; s.z += v.z; s.w += v.w;
    }
    __shared__ float4 red[4][64];
    red[w][lane] = s;
    __syncthreads();
    if (w == 0) {
        float4 a0 = red[0][lane], a1 = red[1][lane], a2 = red[2][lane], a3 = red[3][lane];
        float4 o;
        o.x = (a0.x + a1.x + a2.x + a3.x) * (1.0f / SS);
        o.y = (a0.y + a1.y + a2.y + a3.y) * (1.0f / SS);
        o.z = (a0.z + a1.z + a2.z + a3.z) * (1.0f / SS);
        o.w = (a0.w + a1.w + a2.w + a3.w) * (1.0f / SS);
        ((float4*)(drep + (size_t)b * HH))[c4] = o;
    }
}

// ---------------- K1: t = d_rep @ W_rel^T  (fp32 NT, 64x64x16; 0.6 GFLOP) ----------------
__global__ __launch_bounds__(256) void k_gemm_nt(const float* __restrict__ A,
                                                 const float* __restrict__ Bm,
                                                 float* __restrict__ C,
                                                 int N, int K) {
    __shared__ float As[64 * 20];
    __shared__ float Bs[64 * 20];
    int tid = threadIdx.x;
    int ty = tid >> 4, tx = tid & 15;
    int m0 = blockIdx.y * 64, n0 = blockIdx.x * 64;
    int lr = tid >> 2, lc = (tid & 3) * 4;
    float acc[4][4] = {};
    for (int kt = 0; kt < K; kt += 16) {
        *(float4*)(As + lr * 20 + lc) = *(const float4*)(A + (size_t)(m0 + lr) * K + kt + lc);
        *(float4*)(Bs + lr * 20 + lc) = *(const float4*)(Bm + (size_t)(n0 + lr) * K + kt + lc);
        __syncthreads();
        #pragma unroll
        for (int k = 0; k < 16; k += 2) {
            float2 ar[4], br[4];
            #pragma unroll
            for (int ii = 0; ii < 4; ++ii) ar[ii] = *(const float2*)(As + (ty + 16 * ii) * 20 + k);
            #pragma unroll
            for (int jj = 0; jj < 4; ++jj) br[jj] = *(const float2*)(Bs + (tx + 16 * jj) * 20 + k);
            #pragma unroll
            for (int ii = 0; ii < 4; ++ii)
                #pragma unroll
                for (int jj = 0; jj < 4; ++jj)
                    acc[ii][jj] = fmaf(ar[ii].y, br[jj].y, fmaf(ar[ii].x, br[jj].x, acc[ii][jj]));
        }
        __syncthreads();
    }
    #pragma unroll
    for (int ii = 0; ii < 4; ++ii)
        #pragma unroll
        for (int jj = 0; jj < 4; ++jj)
            C[(size_t)(m0 + ty + 16 * ii) * N + n0 + tx + 16 * jj] = acc[ii][jj];
}

// ---------------- K_splitw: W(K x N) -> Wt_h/Wt_l (N x K) bf16 split ----------------
__global__ __launch_bounds__(256) void k_splitw(const float* __restrict__ W,
                                                __bf16* __restrict__ th,
                                                __bf16* __restrict__ tl) {
    __shared__ float tile[32][33];
    int bn = blockIdx.x * 32, bk = blockIdx.y * 32;
    int tx = threadIdx.x & 31, ty = threadIdx.x >> 5;
    for (int r = ty; r < 32; r += 8)
        tile[r][tx] = W[(size_t)(bk + r) * HH + bn + tx];
    __syncthreads();
    for (int r = ty; r < 32; r += 8) {
        float v = tile[tx][r];
        __bf16 hv = (__bf16)v;
        size_t idx = (size_t)(bn + r) * HH + bk + tx;
        th[idx] = hv;
        tl[idx] = (__bf16)(v - (float)hv);
    }
}

// ---------------- K_split+contrel: split X chunk to bf16 hi/lo AND a[b,i]=X[b,i]·u[b]+b00 ----------------
__global__ __launch_bounds__(512) void k_split_contrel(const float* __restrict__ X,
                                                       const float* __restrict__ Wc,
                                                       const float* __restrict__ tmat,
                                                       const float* __restrict__ bmat,
                                                       __bf16* __restrict__ Xh,
                                                       __bf16* __restrict__ Xl,
                                                       float* __restrict__ avec,
                                                       int b_off) {
    __shared__ float4 u4[192];
    int lb = blockIdx.x, half = blockIdx.y;
    int b = b_off + lb;
    int tid = threadIdx.x, lane = tid & 63, w = tid >> 6;
    for (int c = tid; c < 192; c += 512) {
        float4 wc = ((const float4*)Wc)[c];
        float4 tm = ((const float4*)(tmat + (size_t)b * HH))[c];
        float4 o = {wc.x + tm.x, wc.y + tm.y, wc.z + tm.z, wc.w + tm.w};
        u4[c] = o;
    }
    __syncthreads();
    float b00 = bmat[0];
    const float4* xb = (const float4*)(X + (size_t)b * SS * HH);
    bf16x4* xh4 = (bf16x4*)(Xh + (size_t)lb * SS * HH);
    bf16x4* xl4 = (bf16x4*)(Xl + (size_t)lb * SS * HH);
    int rend = half * 50 + 50;
    for (int r = half * 50 + w; r < rend; r += 8) {
        float s = 0.f;
        #pragma unroll
        for (int cc = 0; cc < 3; ++cc) {
            int c = cc * 64 + lane;
            float4 v = xb[r * 192 + c];
            float4 uu = u4[c];
            s = fmaf(v.x, uu.x, fmaf(v.y, uu.y, fmaf(v.z, uu.z, fmaf(v.w, uu.w, s))));
            bf16x4 hv, lv;
            hv[0] = (__bf16)v.x; lv[0] = (__bf16)(v.x - (float)hv[0]);
            hv[1] = (__bf16)v.y; lv[1] = (__bf16)(v.y - (float)hv[1]);
            hv[2] = (__bf16)v.z; lv[2] = (__bf16)(v.z - (float)hv[2]);
            hv[3] = (__bf16)v.w; lv[3] = (__bf16)(v.w - (float)hv[3]);
            xh4[r * 192 + c] = hv;
            xl4[r * 192 + c] = lv;
        }
        #pragma unroll
        for (int off = 32; off > 0; off >>= 1) s += __shfl_down(s, off);
        if (lane == 0) avec[(size_t)b * SS + r] = s + b00;
    }
}

// ---------------- K3: GEMM1 MFMA 32x32x16  Y = X @ W  (NT, split-bf16) ----------------
// R7: 256x256 tile (R6's low LDS-traffic ratio) + SINGLE 64 KB buffer -> 2 blocks/CU
// (R5's co-residency). Cross-block TLP hides the per-step drain (dbuf was worth <=3us
// at 2 blocks/CU, R2->R4). Staging/compute/epilogue indexing identical to R6 (verified).
__global__ __launch_bounds__(512) void k_gemm1_mfma(const __bf16* __restrict__ Ah_g,
                                                    const __bf16* __restrict__ Al_g,
                                                    const __bf16* __restrict__ Bh_g,
                                                    const __bf16* __restrict__ Bl_g,
                                                    __bf16* __restrict__ Yh,
                                                    __bf16* __restrict__ Yl) {
    __shared__ __align__(16) __bf16 lds[32768];        // 64 KB, single buffer
    const int tid = threadIdx.x;
    const int wave = tid >> 6, lane = tid & 63;
    const int wy = wave >> 2, wx = wave & 3;           // 2 x 4 wave grid, 128x64 per wave
    // bijective XCD remap (m204)
    const int nwg = gridDim.x;
    const int lid = blockIdx.x;
    const int q8 = nwg >> 3, r8 = nwg & 7;
    const int xcd = lid & 7, idx = lid >> 3;
    const int tile = (xcd < r8 ? xcd * (q8 + 1) : r8 * (q8 + 1) + (xcd - r8) * q8) + idx;
    const size_t m0 = (size_t)(tile / 3) * 256;
    const int n0 = (tile % 3) * 256;

    const int srow = tid >> 2;                          // 0..127 (+128 for second gld16)
    const int scol = ((lane & 3) ^ ((lane >> 3) & 3)) * 8;   // pre-swizzled global source chunk
    const int wbase = wave * 512;

    const int arow = wy * 128 + (lane & 31);            // + ti*32
    const int brow = wx * 64 + (lane & 31);             // + tj*32
    const int sw = (lane >> 1) & 3;

    f32x16 acc[4][2] = {};

    auto stage = [&](int kt) {
        const size_t ga0 = (m0 + srow) * HH + kt + scol;
        const size_t ga1 = ga0 + (size_t)128 * HH;
        const size_t gb0 = (size_t)(n0 + srow) * HH + kt + scol;
        const size_t gb1 = gb0 + (size_t)128 * HH;
        gld16(Ah_g + ga0, lds + wbase);                 // Ah piece: [0, 8192)
        gld16(Ah_g + ga1, lds + 4096 + wbase);
        gld16(Al_g + ga0, lds + 8192 + wbase);          // Al piece
        gld16(Al_g + ga1, lds + 12288 + wbase);
        gld16(Bh_g + gb0, lds + 16384 + wbase);         // Bh piece
        gld16(Bh_g + gb1, lds + 20480 + wbase);
        gld16(Bl_g + gb0, lds + 24576 + wbase);         // Bl piece
        gld16(Bl_g + gb1, lds + 28672 + wbase);
    };
    auto compute = [&]() {
        const __bf16* Ah_s = lds;
        const __bf16* Al_s = lds + 8192;
        const __bf16* Bh_s = lds + 16384;
        const __bf16* Bl_s = lds + 24576;
        #pragma unroll
        for (int kh = 0; kh < 2; ++kh) {
            const int ko = (((kh << 1) + (lane >> 5)) ^ sw) << 3;
            bf16x8 fah[4], fal[4], fbh[2], fbl[2];
            #pragma unroll
            for (int t = 0; t < 4; ++t) {
                fah[t] = *(const bf16x8*)(Ah_s + (arow + t * 32) * 32 + ko);
                fal[t] = *(const bf16x8*)(Al_s + (arow + t * 32) * 32 + ko);
            }
            #pragma unroll
            for (int t = 0; t < 2; ++t) {
                fbh[t] = *(const bf16x8*)(Bh_s + (brow + t * 32) * 32 + ko);
                fbl[t] = *(const bf16x8*)(Bl_s + (brow + t * 32) * 32 + ko);
            }
            #pragma unroll
            for (int ti = 0; ti < 4; ++ti)
                #pragma unroll
                for (int tj = 0; tj < 2; ++tj) {
                    acc[ti][tj] = __builtin_amdgcn_mfma_f32_32x32x16_bf16(fal[ti], fbh[tj], acc[ti][tj], 0, 0, 0);
                    acc[ti][tj] = __builtin_amdgcn_mfma_f32_32x32x16_bf16(fah[ti], fbl[tj], acc[ti][tj], 0, 0, 0);
                    acc[ti][tj] = __builtin_amdgcn_mfma_f32_32x32x16_bf16(fah[ti], fbh[tj], acc[ti][tj], 0, 0, 0);
                }
        }
    };

    for (int kt = 0; kt < HH; kt += 32) {
        stage(kt);
        asm volatile("s_waitcnt vmcnt(0)" ::: "memory");
        __builtin_amdgcn_s_barrier();
        compute();
        __builtin_amdgcn_s_barrier();                   // all reads done before next overwrite
    }

    // 32x32 C/D: col = lane&31, row = (reg&3) + 8*(reg>>2) + 4*(lane>>5)  [m74/m101]
    const int rbase = 4 * (lane >> 5);
    const int colb = lane & 31;
    #pragma unroll
    for (int ti = 0; ti < 4; ++ti) {
        #pragma unroll
        for (int tj = 0; tj < 2; ++tj) {
            int col = n0 + wx * 64 + tj * 32 + colb;
            #pragma unroll
            for (int r = 0; r < 16; ++r) {
                int row = wy * 128 + ti * 32 + (r & 3) + 8 * (r >> 2) + rbase;
                float v = acc[ti][tj][r];
                __bf16 hv = (__bf16)v;
                size_t idx = (m0 + row) * HH + col;
                Yh[idx] = hv;
                Yl[idx] = (__bf16)(v - (float)hv);
            }
        }
    }
}

// ---------------- K4: GEMM2 MFMA 32x32x16  q[b] = sigmoid(Y[b] @ X[b]^T + a[b,i]) ----------------
// One 128x128 block per batch. 128² + counted-vmcnt dbuf structure (unchanged from R5).
__global__ __launch_bounds__(256) void k_gemm2_mfma(const __bf16* __restrict__ Yh,
                                                    const __bf16* __restrict__ Yl,
                                                    const __bf16* __restrict__ Xh,
                                                    const __bf16* __restrict__ Xl,
                                                    const float* __restrict__ avec,
                                                    float* __restrict__ q, int b_off) {
    __shared__ __align__(16) __bf16 lds[2 * 4 * 4096];
    __shared__ float av_s[SS];
    const int bl = blockIdx.x;
    const int b = b_off + bl;
    const __bf16* Ah_g = Yh + (size_t)bl * SS * HH;
    const __bf16* Al_g = Yl + (size_t)bl * SS * HH;
    const __bf16* Bh_g = Xh + (size_t)bl * SS * HH;
    const __bf16* Bl_g = Xl + (size_t)bl * SS * HH;
    const int tid = threadIdx.x;
    const int wave = tid >> 6, lane = tid & 63;
    const int wy = wave >> 1, wx = wave & 1;
    if (tid < SS) av_s[tid] = avec[(size_t)b * SS + tid];

    const int srow_raw = wave * 32 + (lane >> 2);
    const int scol = ((lane & 3) ^ ((lane >> 3) & 3)) * 8;
    const int lds_base = wave * 1024;
    const int r0 = srow_raw < SS ? srow_raw : SS - 1;
    const int r1 = (srow_raw + 16) < SS ? (srow_raw + 16) : SS - 1;

    const int arow = wy * 64 + (lane & 31);
    const int brow = wx * 64 + (lane & 31);
    const int sw = (lane >> 1) & 3;

    f32x16 acc[2][2] = {};

    auto stage = [&](int buf, int kt) {
        __bf16* base = lds + buf * 16384;
        const size_t ga0 = (size_t)r0 * HH + kt + scol;
        const size_t ga1 = (size_t)r1 * HH + kt + scol;
        gld16(Ah_g + ga0, base + lds_base);
        gld16(Ah_g + ga1, base + lds_base + 512);
        gld16(Al_g + ga0, base + 4096 + lds_base);
        gld16(Al_g + ga1, base + 4096 + lds_base + 512);
        gld16(Bh_g + ga0, base + 8192 + lds_base);
        gld16(Bh_g + ga1, base + 8192 + lds_base + 512);
        gld16(Bl_g + ga0, base + 12288 + lds_base);
        gld16(Bl_g + ga1, base + 12288 + lds_base + 512);
    };
    auto compute = [&](int buf) {
        const __bf16* As_h = lds + buf * 16384;
        const __bf16* As_l = As_h + 4096;
        const __bf16* Bs_h = As_h + 8192;
        const __bf16* Bs_l = As_h + 12288;
        #pragma unroll
        for (int kh = 0; kh < 2; ++kh) {
            const int ko = (((kh << 1) + (lane >> 5)) ^ sw) << 3;
            bf16x8 fah[2], fal[2], fbh[2], fbl[2];
            #pragma unroll
            for (int t = 0; t < 2; ++t) {
                fah[t] = *(const bf16x8*)(As_h + (arow + t * 32) * 32 + ko);
                fal[t] = *(const bf16x8*)(As_l + (arow + t * 32) * 32 + ko);
                fbh[t] = *(const bf16x8*)(Bs_h + (brow + t * 32) * 32 + ko);
                fbl[t] = *(const bf16x8*)(Bs_l + (brow + t * 32) * 32 + ko);
            }
            #pragma unroll
            for (int ti = 0; ti < 2; ++ti)
                #pragma unroll
                for (int tj = 0; tj < 2; ++tj) {
                    acc[ti][tj] = __builtin_amdgcn_mfma_f32_32x32x16_bf16(fal[ti], fbh[tj], acc[ti][tj], 0, 0, 0);
                    acc[ti][tj] = __builtin_amdgcn_mfma_f32_32x32x16_bf16(fah[ti], fbl[tj], acc[ti][tj], 0, 0, 0);
                    acc[ti][tj] = __builtin_amdgcn_mfma_f32_32x32x16_bf16(fah[ti], fbh[tj], acc[ti][tj], 0, 0, 0);
                }
        }
    };

    stage(0, 0);
    int cur = 0;
    for (int kt = 32; kt < HH; kt += 32) {
        stage(cur ^ 1, kt);
        asm volatile("s_waitcnt vmcnt(8)" ::: "memory");
        __builtin_amdgcn_s_barrier();
        compute(cur);
        __builtin_amdgcn_s_barrier();
        cur ^= 1;
    }
    asm volatile("s_waitcnt vmcnt(0)" ::: "memory");
    __builtin_amdgcn_s_barrier();
    compute(cur);

    float* qb = q + (size_t)b * SS * SS;
    const int rbase = 4 * (lane >> 5);
    const int colb = lane & 31;
    #pragma unroll
    for (int ti = 0; ti < 2; ++ti) {
        #pragma unroll
        for (int tj = 0; tj < 2; ++tj) {
            int j = wx * 64 + tj * 32 + colb;
            if (j >= SS) continue;
            #pragma unroll
            for (int r = 0; r < 16; ++r) {
                int i = wy * 64 + ti * 32 + (r & 3) + 8 * (r >> 2) + rbase;
                if (i >= SS) continue;
                float v = acc[ti][tj][r] + av_s[i];
                qb[(size_t)i * SS + j] = 1.0f / (1.0f + __expf(-v));
            }
        }
    }
}

// ---------------- K5: colsum + fixed-point solve, M held in registers ----------------
__global__ __launch_bounds__(128) void k_solve(const float* __restrict__ q,
                                               float* __restrict__ out) {
    __shared__ __align__(16) float m[SS * SS];
    __shared__ __align__(16) float csinv[SS];
    __shared__ __align__(16) float x0[SS], x1[SS];
    int b = blockIdx.x, tid = threadIdx.x;
    const float* qb = q + (size_t)b * SS * SS;
    for (int e4 = tid; e4 < SS * SS / 4; e4 += 128)
        *(float4*)(m + e4 * 4) = *(const float4*)(qb + (size_t)e4 * 4);
    __syncthreads();
    if (tid < SS) {
        float s = 0.f;
        for (int i = 0; i < SS; ++i) s += m[i * SS + tid];
        csinv[tid] = 0.8f / s;
        x0[tid] = 1.0f / SS;
    }
    __syncthreads();
    float4 mreg[25];
    if (tid < SS) {
        #pragma unroll
        for (int j4 = 0; j4 < 25; ++j4) {
            float4 mv = *(const float4*)(m + tid * SS + j4 * 4);
            float4 cv = *(const float4*)(csinv + j4 * 4);
            mreg[j4].x = mv.x * cv.x;
            mreg[j4].y = mv.y * cv.y;
            mreg[j4].z = mv.z * cv.z;
            mreg[j4].w = mv.w * cv.w;
        }
    } else {
        #pragma unroll
        for (int j4 = 0; j4 < 25; ++j4) mreg[j4] = float4{0, 0, 0, 0};
    }
    __syncthreads();
    #pragma unroll 1
    for (int it = 0; it < 56; ++it) {
        const float* xr = (it & 1) ? x1 : x0;
        float* xw = (it & 1) ? x0 : x1;
        if (tid < SS) {
            float sx = 0.f, sy = 0.f, sz = 0.f, sw = 0.f;
            #pragma unroll
            for (int j4 = 0; j4 < 25; ++j4) {
                float4 xv = *(const float4*)(xr + j4 * 4);
                sx = fmaf(mreg[j4].x, xv.x, sx);
                sy = fmaf(mreg[j4].y, xv.y, sy);
                sz = fmaf(mreg[j4].z, xv.z, sz);
                sw = fmaf(mreg[j4].w, xv.w, sw);
            }
            xw[tid] = 0.002f + ((sx + sy) + (sz + sw));
        }
        __syncthreads();
    }
    if (tid < SS) out[(size_t)b * SS + tid] = x0[tid];
}

extern "C" void kernel_launch(void* const* d_in, const int* in_sizes, int n_in,
                              void* d_out, int out_size, void* d_ws, size_t ws_size,
                              hipStream_t stream) {
    (void)in_sizes; (void)n_in; (void)out_size;
    const float* X    = (const float*)d_in[0];
    const float* Wc   = (const float*)d_in[2];
    const float* Wsim = (const float*)d_in[3];
    const float* Wrel = (const float*)d_in[4];
    const float* bmat = (const float*)d_in[5];
    float* out = (float*)d_out;

    char* ws = (char*)d_ws;
    size_t off = 0;
    float*  qbuf = (float*)(ws + off);  off += (size_t)BB * SS * SS * 4;
    float*  drep = (float*)(ws + off);  off += (size_t)BB * HH * 4;
    float*  tmat = (float*)(ws + off);  off += (size_t)BB * HH * 4;
    float*  avec = (float*)(ws + off);  off += (size_t)BB * SS * 4;
    __bf16* Wth  = (__bf16*)(ws + off); off += (size_t)HH * HH * 2;
    __bf16* Wtl  = (__bf16*)(ws + off); off += (size_t)HH * HH * 2;

    int CB = 512;
    while (CB > 128 && off + 4 * (size_t)CB * SS * HH * 2 > ws_size) CB >>= 1;
    size_t xsz = (size_t)CB * SS * HH * 2;
    __bf16* Xh = (__bf16*)(ws + off); off += xsz;
    __bf16* Xl = (__bf16*)(ws + off); off += xsz;
    __bf16* Yh = (__bf16*)(ws + off); off += xsz;
    __bf16* Yl = (__bf16*)(ws + off); off += xsz;

    k_drep<<<dim3(BB, 3), 256, 0, stream>>>(X, drep);
    k_gemm_nt<<<dim3(HH / 64, BB / 64), 256, 0, stream>>>(drep, Wrel, tmat, HH, HH);
    k_splitw<<<dim3(HH / 32, HH / 32), 256, 0, stream>>>(Wsim, Wth, Wtl);

    for (int c = 0; c < BB; c += CB) {
        k_split_contrel<<<dim3(CB, 2), 512, 0, stream>>>(X + (size_t)c * SS * HH, Wc, tmat, bmat, Xh, Xl, avec, c);
        int nblk1 = (CB * SS / 256) * (HH / 256);   // 256x256 tiles
        k_gemm1_mfma<<<nblk1, 512, 0, stream>>>(Xh, Xl, Wth, Wtl, Yh, Yl);
        k_gemm2_mfma<<<CB, 256, 0, stream>>>(Yh, Yl, Xh, Xl, avec, qbuf, c);
    }
    k_solve<<<BB, 128, 0, stream>>>(qbuf, out);
}

// Round 8
// 725.796 us; speedup vs baseline: 1.0274x; 1.0274x over previous
//
#include <hip/hip_runtime.h>
#include <math.h>

#define BB 512
#define SS 100
#define HH 768

typedef __bf16 bf16x8 __attribute__((ext_vector_type(8)));
typedef __bf16 bf16x4 __attribute__((ext_vector_type(4)));
typedef float f32x4 __attribute__((ext_vector_type(4)));
typedef float f32x16 __attribute__((ext_vector_type(16)));

__device__ __forceinline__ void gld16(const void* g, void* l) {
    __builtin_amdgcn_global_load_lds((const __attribute__((address_space(1))) char*)g,
                                     (__attribute__((address_space(3))) char*)l, 16, 0, 0);
}

// ---------------- K0: d_rep[b,h] = mean_s X[b,s,h]  (coalesced float4 col-reduce) ----------------
__global__ __launch_bounds__(256) void k_drep(const float* __restrict__ X,
                                              float* __restrict__ drep) {
    int b = blockIdx.x, g = blockIdx.y;
    int lane = threadIdx.x & 63, w = threadIdx.x >> 6;
    const float4* xb = (const float4*)(X + (size_t)b * SS * HH);
    int c4 = g * 64 + lane;
    float4 s = {0.f, 0.f, 0.f, 0.f};
    for (int r = w; r < SS; r += 4) {
        float4 v = xb[r * 192 + c4];
        s.x += v.x; s.y += v.y; s.z += v.z; s.w += v.w;
    }
    __shared__ float4 red[4][64];
    red[w][lane] = s;
    __syncthreads();
    if (w == 0) {
        float4 a0 = red[0][lane], a1 = red[1][lane], a2 = red[2][lane], a3 = red[3][lane];
        float4 o;
        o.x = (a0.x + a1.x + a2.x + a3.x) * (1.0f / SS);
        o.y = (a0.y + a1.y + a2.y + a3.y) * (1.0f / SS);
        o.z = (a0.z + a1.z + a2.z + a3.z) * (1.0f / SS);
        o.w = (a0.w + a1.w + a2.w + a3.w) * (1.0f / SS);
        ((float4*)(drep + (size_t)b * HH))[c4] = o;
    }
}

// ---------------- K1: t = d_rep @ W_rel^T  (fp32 NT, 64x64x16; 0.6 GFLOP) ----------------
__global__ __launch_bounds__(256) void k_gemm_nt(const float* __restrict__ A,
                                                 const float* __restrict__ Bm,
                                                 float* __restrict__ C,
                                                 int N, int K) {
    __shared__ float As[64 * 20];
    __shared__ float Bs[64 * 20];
    int tid = threadIdx.x;
    int ty = tid >> 4, tx = tid & 15;
    int m0 = blockIdx.y * 64, n0 = blockIdx.x * 64;
    int lr = tid >> 2, lc = (tid & 3) * 4;
    float acc[4][4] = {};
    for (int kt = 0; kt < K; kt += 16) {
        *(float4*)(As + lr * 20 + lc) = *(const float4*)(A + (size_t)(m0 + lr) * K + kt + lc);
        *(float4*)(Bs + lr * 20 + lc) = *(const float4*)(Bm + (size_t)(n0 + lr) * K + kt + lc);
        __syncthreads();
        #pragma unroll
        for (int k = 0; k < 16; k += 2) {
            float2 ar[4], br[4];
            #pragma unroll
            for (int ii = 0; ii < 4; ++ii) ar[ii] = *(const float2*)(As + (ty + 16 * ii) * 20 + k);
            #pragma unroll
            for (int jj = 0; jj < 4; ++jj) br[jj] = *(const float2*)(Bs + (tx + 16 * jj) * 20 + k);
            #pragma unroll
            for (int ii = 0; ii < 4; ++ii)
                #pragma unroll
                for (int jj = 0; jj < 4; ++jj)
                    acc[ii][jj] = fmaf(ar[ii].y, br[jj].y, fmaf(ar[ii].x, br[jj].x, acc[ii][jj]));
        }
        __syncthreads();
    }
    #pragma unroll
    for (int ii = 0; ii < 4; ++ii)
        #pragma unroll
        for (int jj = 0; jj < 4; ++jj)
            C[(size_t)(m0 + ty + 16 * ii) * N + n0 + tx + 16 * jj] = acc[ii][jj];
}

// ---------------- K_splitw: W(K x N) -> Wt_h/Wt_l (N x K) bf16 split ----------------
__global__ __launch_bounds__(256) void k_splitw(const float* __restrict__ W,
                                                __bf16* __restrict__ th,
                                                __bf16* __restrict__ tl) {
    __shared__ float tile[32][33];
    int bn = blockIdx.x * 32, bk = blockIdx.y * 32;
    int tx = threadIdx.x & 31, ty = threadIdx.x >> 5;
    for (int r = ty; r < 32; r += 8)
        tile[r][tx] = W[(size_t)(bk + r) * HH + bn + tx];
    __syncthreads();
    for (int r = ty; r < 32; r += 8) {
        float v = tile[tx][r];
        __bf16 hv = (__bf16)v;
        size_t idx = (size_t)(bn + r) * HH + bk + tx;
        th[idx] = hv;
        tl[idx] = (__bf16)(v - (float)hv);
    }
}

// ---------------- K_split+contrel: split X chunk to bf16 hi/lo AND a[b,i]=X[b,i]·u[b]+b00 ----------------
__global__ __launch_bounds__(512) void k_split_contrel(const float* __restrict__ X,
                                                       const float* __restrict__ Wc,
                                                       const float* __restrict__ tmat,
                                                       const float* __restrict__ bmat,
                                                       __bf16* __restrict__ Xh,
                                                       __bf16* __restrict__ Xl,
                                                       float* __restrict__ avec,
                                                       int b_off) {
    __shared__ float4 u4[192];
    int lb = blockIdx.x, half = blockIdx.y;
    int b = b_off + lb;
    int tid = threadIdx.x, lane = tid & 63, w = tid >> 6;
    for (int c = tid; c < 192; c += 512) {
        float4 wc = ((const float4*)Wc)[c];
        float4 tm = ((const float4*)(tmat + (size_t)b * HH))[c];
        float4 o = {wc.x + tm.x, wc.y + tm.y, wc.z + tm.z, wc.w + tm.w};
        u4[c] = o;
    }
    __syncthreads();
    float b00 = bmat[0];
    const float4* xb = (const float4*)(X + (size_t)b * SS * HH);
    bf16x4* xh4 = (bf16x4*)(Xh + (size_t)lb * SS * HH);
    bf16x4* xl4 = (bf16x4*)(Xl + (size_t)lb * SS * HH);
    int rend = half * 50 + 50;
    for (int r = half * 50 + w; r < rend; r += 8) {
        float s = 0.f;
        #pragma unroll
        for (int cc = 0; cc < 3; ++cc) {
            int c = cc * 64 + lane;
            float4 v = xb[r * 192 + c];
            float4 uu = u4[c];
            s = fmaf(v.x, uu.x, fmaf(v.y, uu.y, fmaf(v.z, uu.z, fmaf(v.w, uu.w, s))));
            bf16x4 hv, lv;
            hv[0] = (__bf16)v.x; lv[0] = (__bf16)(v.x - (float)hv[0]);
            hv[1] = (__bf16)v.y; lv[1] = (__bf16)(v.y - (float)hv[1]);
            hv[2] = (__bf16)v.z; lv[2] = (__bf16)(v.z - (float)hv[2]);
            hv[3] = (__bf16)v.w; lv[3] = (__bf16)(v.w - (float)hv[3]);
            xh4[r * 192 + c] = hv;
            xl4[r * 192 + c] = lv;
        }
        #pragma unroll
        for (int off = 32; off > 0; off >>= 1) s += __shfl_down(s, off);
        if (lane == 0) avec[(size_t)b * SS + r] = s + b00;
    }
}

// ---------------- K3: GEMM1 MFMA 32x32x16  Y = X @ W  (NT, split-bf16, 128x128, BK=32) ----------------
// R8: restored R5 structure (session best, 228us): dbuf 64KB + counted vmcnt(8) + XOR swizzle.
// Instrumentation split: launched as 3 sequential M-chunk dispatches (m_lo/m_cnt) so each runs
// ~76-85us -> the top-5 profile table must reveal every other kernel >80us (they were invisible
// behind 228us gemm1 repeats). Zero-cost: same work, same access pattern. m204-bijective XCD remap.
__global__ __launch_bounds__(256) void k_gemm1_mfma(const __bf16* __restrict__ Ah_g,
                                                    const __bf16* __restrict__ Al_g,
                                                    const __bf16* __restrict__ Bh_g,
                                                    const __bf16* __restrict__ Bl_g,
                                                    __bf16* __restrict__ Yh,
                                                    __bf16* __restrict__ Yl,
                                                    int m_lo) {
    __shared__ __align__(16) __bf16 lds[2 * 4 * 4096];   // 64 KB, 2 buffers
    const int tid = threadIdx.x;
    const int wave = tid >> 6, lane = tid & 63;
    const int wy = wave >> 1, wx = wave & 1;
    // m204-bijective XCD remap over this chunk's 1-D grid
    const int nwg = gridDim.x;
    const int lid = blockIdx.x;
    const int q8 = nwg >> 3, r8 = nwg & 7;
    const int xcd = lid & 7, sidx = lid >> 3;
    const int tile = (xcd < r8 ? xcd * (q8 + 1) : r8 * (q8 + 1) + (xcd - r8) * q8) + sidx;
    const size_t m0 = (size_t)(m_lo + tile / 6) * 128;
    const int n0 = (tile % 6) * 128;

    const int srow = wave * 32 + (lane >> 2);
    const int scol = ((lane & 3) ^ ((lane >> 3) & 3)) * 8;   // pre-swizzled global source chunk
    const int lds_base = wave * 1024;

    const int arow = wy * 64 + (lane & 31);   // + t*32
    const int brow = wx * 64 + (lane & 31);
    const int sw = (lane >> 1) & 3;

    f32x16 acc[2][2] = {};

    auto stage = [&](int buf, int kt) {
        __bf16* base = lds + buf * 16384;
        const size_t ga0 = (m0 + srow) * HH + kt + scol;
        const size_t ga1 = ga0 + (size_t)16 * HH;
        const size_t gb0 = (size_t)(n0 + srow) * HH + kt + scol;
        const size_t gb1 = gb0 + (size_t)16 * HH;
        gld16(Ah_g + ga0, base + lds_base);
        gld16(Ah_g + ga1, base + lds_base + 512);
        gld16(Al_g + ga0, base + 4096 + lds_base);
        gld16(Al_g + ga1, base + 4096 + lds_base + 512);
        gld16(Bh_g + gb0, base + 8192 + lds_base);
        gld16(Bh_g + gb1, base + 8192 + lds_base + 512);
        gld16(Bl_g + gb0, base + 12288 + lds_base);
        gld16(Bl_g + gb1, base + 12288 + lds_base + 512);
    };
    auto compute = [&](int buf) {
        const __bf16* As_h = lds + buf * 16384;
        const __bf16* As_l = As_h + 4096;
        const __bf16* Bs_h = As_h + 8192;
        const __bf16* Bs_l = As_h + 12288;
        #pragma unroll
        for (int kh = 0; kh < 2; ++kh) {
            const int ko = (((kh << 1) + (lane >> 5)) ^ sw) << 3;
            bf16x8 fah[2], fal[2], fbh[2], fbl[2];
            #pragma unroll
            for (int t = 0; t < 2; ++t) {
                fah[t] = *(const bf16x8*)(As_h + (arow + t * 32) * 32 + ko);
                fal[t] = *(const bf16x8*)(As_l + (arow + t * 32) * 32 + ko);
                fbh[t] = *(const bf16x8*)(Bs_h + (brow + t * 32) * 32 + ko);
                fbl[t] = *(const bf16x8*)(Bs_l + (brow + t * 32) * 32 + ko);
            }
            #pragma unroll
            for (int ti = 0; ti < 2; ++ti)
                #pragma unroll
                for (int tj = 0; tj < 2; ++tj) {
                    acc[ti][tj] = __builtin_amdgcn_mfma_f32_32x32x16_bf16(fal[ti], fbh[tj], acc[ti][tj], 0, 0, 0);
                    acc[ti][tj] = __builtin_amdgcn_mfma_f32_32x32x16_bf16(fah[ti], fbl[tj], acc[ti][tj], 0, 0, 0);
                    acc[ti][tj] = __builtin_amdgcn_mfma_f32_32x32x16_bf16(fah[ti], fbh[tj], acc[ti][tj], 0, 0, 0);
                }
        }
    };

    stage(0, 0);                                  // 8 outstanding (buf0)
    int cur = 0;
    for (int kt = 32; kt < HH; kt += 32) {
        stage(cur ^ 1, kt);                       // +8 -> 16 outstanding
        asm volatile("s_waitcnt vmcnt(8)" ::: "memory");   // buf[cur]'s 8 landed; 8 stay in flight
        __builtin_amdgcn_s_barrier();             // all waves' buf[cur] complete
        compute(cur);
        __builtin_amdgcn_s_barrier();             // all reads of buf[cur] done -> may overwrite next iter
        cur ^= 1;
    }
    asm volatile("s_waitcnt vmcnt(0)" ::: "memory");
    __builtin_amdgcn_s_barrier();
    compute(cur);

    // 32x32 C/D: col = lane&31, row = (reg&3) + 8*(reg>>2) + 4*(lane>>5)  [m74/m101]
    const int rbase = 4 * (lane >> 5);
    const int colb = lane & 31;
    #pragma unroll
    for (int ti = 0; ti < 2; ++ti) {
        #pragma unroll
        for (int tj = 0; tj < 2; ++tj) {
            int col = n0 + wx * 64 + tj * 32 + colb;
            #pragma unroll
            for (int r = 0; r < 16; ++r) {
                int row = wy * 64 + ti * 32 + (r & 3) + 8 * (r >> 2) + rbase;
                float v = acc[ti][tj][r];
                __bf16 hv = (__bf16)v;
                size_t idx = (m0 + row) * HH + col;
                Yh[idx] = hv;
                Yl[idx] = (__bf16)(v - (float)hv);
            }
        }
    }
}

// ---------------- K4: GEMM2 MFMA 32x32x16  q[b] = sigmoid(Y[b] @ X[b]^T + a[b,i]) ----------------
// One 128x128 block per batch. 128² + counted-vmcnt dbuf structure (unchanged from R5).
__global__ __launch_bounds__(256) void k_gemm2_mfma(const __bf16* __restrict__ Yh,
                                                    const __bf16* __restrict__ Yl,
                                                    const __bf16* __restrict__ Xh,
                                                    const __bf16* __restrict__ Xl,
                                                    const float* __restrict__ avec,
                                                    float* __restrict__ q, int b_off) {
    __shared__ __align__(16) __bf16 lds[2 * 4 * 4096];
    __shared__ float av_s[SS];
    const int bl = blockIdx.x;
    const int b = b_off + bl;
    const __bf16* Ah_g = Yh + (size_t)bl * SS * HH;
    const __bf16* Al_g = Yl + (size_t)bl * SS * HH;
    const __bf16* Bh_g = Xh + (size_t)bl * SS * HH;
    const __bf16* Bl_g = Xl + (size_t)bl * SS * HH;
    const int tid = threadIdx.x;
    const int wave = tid >> 6, lane = tid & 63;
    const int wy = wave >> 1, wx = wave & 1;
    if (tid < SS) av_s[tid] = avec[(size_t)b * SS + tid];

    const int srow_raw = wave * 32 + (lane >> 2);
    const int scol = ((lane & 3) ^ ((lane >> 3) & 3)) * 8;
    const int lds_base = wave * 1024;
    const int r0 = srow_raw < SS ? srow_raw : SS - 1;
    const int r1 = (srow_raw + 16) < SS ? (srow_raw + 16) : SS - 1;

    const int arow = wy * 64 + (lane & 31);
    const int brow = wx * 64 + (lane & 31);
    const int sw = (lane >> 1) & 3;

    f32x16 acc[2][2] = {};

    auto stage = [&](int buf, int kt) {
        __bf16* base = lds + buf * 16384;
        const size_t ga0 = (size_t)r0 * HH + kt + scol;
        const size_t ga1 = (size_t)r1 * HH + kt + scol;
        gld16(Ah_g + ga0, base + lds_base);
        gld16(Ah_g + ga1, base + lds_base + 512);
        gld16(Al_g + ga0, base + 4096 + lds_base);
        gld16(Al_g + ga1, base + 4096 + lds_base + 512);
        gld16(Bh_g + ga0, base + 8192 + lds_base);
        gld16(Bh_g + ga1, base + 8192 + lds_base + 512);
        gld16(Bl_g + ga0, base + 12288 + lds_base);
        gld16(Bl_g + ga1, base + 12288 + lds_base + 512);
    };
    auto compute = [&](int buf) {
        const __bf16* As_h = lds + buf * 16384;
        const __bf16* As_l = As_h + 4096;
        const __bf16* Bs_h = As_h + 8192;
        const __bf16* Bs_l = As_h + 12288;
        #pragma unroll
        for (int kh = 0; kh < 2; ++kh) {
            const int ko = (((kh << 1) + (lane >> 5)) ^ sw) << 3;
            bf16x8 fah[2], fal[2], fbh[2], fbl[2];
            #pragma unroll
            for (int t = 0; t < 2; ++t) {
                fah[t] = *(const bf16x8*)(As_h + (arow + t * 32) * 32 + ko);
                fal[t] = *(const bf16x8*)(As_l + (arow + t * 32) * 32 + ko);
                fbh[t] = *(const bf16x8*)(Bs_h + (brow + t * 32) * 32 + ko);
                fbl[t] = *(const bf16x8*)(Bs_l + (brow + t * 32) * 32 + ko);
            }
            #pragma unroll
            for (int ti = 0; ti < 2; ++ti)
                #pragma unroll
                for (int tj = 0; tj < 2; ++tj) {
                    acc[ti][tj] = __builtin_amdgcn_mfma_f32_32x32x16_bf16(fal[ti], fbh[tj], acc[ti][tj], 0, 0, 0);
                    acc[ti][tj] = __builtin_amdgcn_mfma_f32_32x32x16_bf16(fah[ti], fbl[tj], acc[ti][tj], 0, 0, 0);
                    acc[ti][tj] = __builtin_amdgcn_mfma_f32_32x32x16_bf16(fah[ti], fbh[tj], acc[ti][tj], 0, 0, 0);
                }
        }
    };

    stage(0, 0);
    int cur = 0;
    for (int kt = 32; kt < HH; kt += 32) {
        stage(cur ^ 1, kt);
        asm volatile("s_waitcnt vmcnt(8)" ::: "memory");
        __builtin_amdgcn_s_barrier();
        compute(cur);
        __builtin_amdgcn_s_barrier();
        cur ^= 1;
    }
    asm volatile("s_waitcnt vmcnt(0)" ::: "memory");
    __builtin_amdgcn_s_barrier();
    compute(cur);

    float* qb = q + (size_t)b * SS * SS;
    const int rbase = 4 * (lane >> 5);
    const int colb = lane & 31;
    #pragma unroll
    for (int ti = 0; ti < 2; ++ti) {
        #pragma unroll
        for (int tj = 0; tj < 2; ++tj) {
            int j = wx * 64 + tj * 32 + colb;
            if (j >= SS) continue;
            #pragma unroll
            for (int r = 0; r < 16; ++r) {
                int i = wy * 64 + ti * 32 + (r & 3) + 8 * (r >> 2) + rbase;
                if (i >= SS) continue;
                float v = acc[ti][tj][r] + av_s[i];
                qb[(size_t)i * SS + j] = 1.0f / (1.0f + __expf(-v));
            }
        }
    }
}

// ---------------- K5: colsum + fixed-point solve, M held in registers ----------------
__global__ __launch_bounds__(128) void k_solve(const float* __restrict__ q,
                                               float* __restrict__ out) {
    __shared__ __align__(16) float m[SS * SS];
    __shared__ __align__(16) float csinv[SS];
    __shared__ __align__(16) float x0[SS], x1[SS];
    int b = blockIdx.x, tid = threadIdx.x;
    const float* qb = q + (size_t)b * SS * SS;
    for (int e4 = tid; e4 < SS * SS / 4; e4 += 128)
        *(float4*)(m + e4 * 4) = *(const float4*)(qb + (size_t)e4 * 4);
    __syncthreads();
    if (tid < SS) {
        float s = 0.f;
        for (int i = 0; i < SS; ++i) s += m[i * SS + tid];
        csinv[tid] = 0.8f / s;
        x0[tid] = 1.0f / SS;
    }
    __syncthreads();
    float4 mreg[25];
    if (tid < SS) {
        #pragma unroll
        for (int j4 = 0; j4 < 25; ++j4) {
            float4 mv = *(const float4*)(m + tid * SS + j4 * 4);
            float4 cv = *(const float4*)(csinv + j4 * 4);
            mreg[j4].x = mv.x * cv.x;
            mreg[j4].y = mv.y * cv.y;
            mreg[j4].z = mv.z * cv.z;
            mreg[j4].w = mv.w * cv.w;
        }
    } else {
        #pragma unroll
        for (int j4 = 0; j4 < 25; ++j4) mreg[j4] = float4{0, 0, 0, 0};
    }
    __syncthreads();
    #pragma unroll 1
    for (int it = 0; it < 56; ++it) {
        const float* xr = (it & 1) ? x1 : x0;
        float* xw = (it & 1) ? x0 : x1;
        if (tid < SS) {
            float sx = 0.f, sy = 0.f, sz = 0.f, sw = 0.f;
            #pragma unroll
            for (int j4 = 0; j4 < 25; ++j4) {
                float4 xv = *(const float4*)(xr + j4 * 4);
                sx = fmaf(mreg[j4].x, xv.x, sx);
                sy = fmaf(mreg[j4].y, xv.y, sy);
                sz = fmaf(mreg[j4].z, xv.z, sz);
                sw = fmaf(mreg[j4].w, xv.w, sw);
            }
            xw[tid] = 0.002f + ((sx + sy) + (sz + sw));
        }
        __syncthreads();
    }
    if (tid < SS) out[(size_t)b * SS + tid] = x0[tid];
}

extern "C" void kernel_launch(void* const* d_in, const int* in_sizes, int n_in,
                              void* d_out, int out_size, void* d_ws, size_t ws_size,
                              hipStream_t stream) {
    (void)in_sizes; (void)n_in; (void)out_size;
    const float* X    = (const float*)d_in[0];
    const float* Wc   = (const float*)d_in[2];
    const float* Wsim = (const float*)d_in[3];
    const float* Wrel = (const float*)d_in[4];
    const float* bmat = (const float*)d_in[5];
    float* out = (float*)d_out;

    char* ws = (char*)d_ws;
    size_t off = 0;
    float*  qbuf = (float*)(ws + off);  off += (size_t)BB * SS * SS * 4;
    float*  drep = (float*)(ws + off);  off += (size_t)BB * HH * 4;
    float*  tmat = (float*)(ws + off);  off += (size_t)BB * HH * 4;
    float*  avec = (float*)(ws + off);  off += (size_t)BB * SS * 4;
    __bf16* Wth  = (__bf16*)(ws + off); off += (size_t)HH * HH * 2;
    __bf16* Wtl  = (__bf16*)(ws + off); off += (size_t)HH * HH * 2;

    int CB = 512;
    while (CB > 128 && off + 4 * (size_t)CB * SS * HH * 2 > ws_size) CB >>= 1;
    size_t xsz = (size_t)CB * SS * HH * 2;
    __bf16* Xh = (__bf16*)(ws + off); off += xsz;
    __bf16* Xl = (__bf16*)(ws + off); off += xsz;
    __bf16* Yh = (__bf16*)(ws + off); off += xsz;
    __bf16* Yl = (__bf16*)(ws + off); off += xsz;

    k_drep<<<dim3(BB, 3), 256, 0, stream>>>(X, drep);
    k_gemm_nt<<<dim3(HH / 64, BB / 64), 256, 0, stream>>>(drep, Wrel, tmat, HH, HH);
    k_splitw<<<dim3(HH / 32, HH / 32), 256, 0, stream>>>(Wsim, Wth, Wtl);

    for (int c = 0; c < BB; c += CB) {
        k_split_contrel<<<dim3(CB, 2), 512, 0, stream>>>(X + (size_t)c * SS * HH, Wc, tmat, bmat, Xh, Xl, avec, c);
        // gemm1 split into 3 M-chunk dispatches (instrumentation: reveal 2nd-tier kernels in top-5)
        int mt_total = CB * SS / 128;               // 400 m-tiles at CB=512
        int mt_chunk = (mt_total + 2) / 3;
        for (int m_lo = 0; m_lo < mt_total; m_lo += mt_chunk) {
            int ct = mt_total - m_lo < mt_chunk ? mt_total - m_lo : mt_chunk;
            k_gemm1_mfma<<<ct * (HH / 128), 256, 0, stream>>>(Xh, Xl, Wth, Wtl, Yh, Yl, m_lo);
        }
        k_gemm2_mfma<<<CB, 256, 0, stream>>>(Yh, Yl, Xh, Xl, avec, qbuf, c);
    }
    k_solve<<<BB, 128, 0, stream>>>(qbuf, out);
}

// Round 9
// 706.277 us; speedup vs baseline: 1.0558x; 1.0276x over previous
//
#include <hip/hip_runtime.h>
#include <math.h>

#define BB 512
#define SS 100
#define HH 768

typedef __bf16 bf16x8 __attribute__((ext_vector_type(8)));
typedef __bf16 bf16x4 __attribute__((ext_vector_type(4)));
typedef float f32x4 __attribute__((ext_vector_type(4)));
typedef float f32x16 __attribute__((ext_vector_type(16)));

__device__ __forceinline__ void gld16(const void* g, void* l) {
    __builtin_amdgcn_global_load_lds((const __attribute__((address_space(1))) char*)g,
                                     (__attribute__((address_space(3))) char*)l, 16, 0, 0);
}

// ---------------- K0: d_rep[b,h] = mean_s X[b,s,h]  (coalesced float4 col-reduce) ----------------
__global__ __launch_bounds__(256) void k_drep(const float* __restrict__ X,
                                              float* __restrict__ drep) {
    int b = blockIdx.x, g = blockIdx.y;
    int lane = threadIdx.x & 63, w = threadIdx.x >> 6;
    const float4* xb = (const float4*)(X + (size_t)b * SS * HH);
    int c4 = g * 64 + lane;
    float4 s = {0.f, 0.f, 0.f, 0.f};
    for (int r = w; r < SS; r += 4) {
        float4 v = xb[r * 192 + c4];
        s.x += v.x; s.y += v.y; s.z += v.z; s.w += v.w;
    }
    __shared__ float4 red[4][64];
    red[w][lane] = s;
    __syncthreads();
    if (w == 0) {
        float4 a0 = red[0][lane], a1 = red[1][lane], a2 = red[2][lane], a3 = red[3][lane];
        float4 o;
        o.x = (a0.x + a1.x + a2.x + a3.x) * (1.0f / SS);
        o.y = (a0.y + a1.y + a2.y + a3.y) * (1.0f / SS);
        o.z = (a0.z + a1.z + a2.z + a3.z) * (1.0f / SS);
        o.w = (a0.w + a1.w + a2.w + a3.w) * (1.0f / SS);
        ((float4*)(drep + (size_t)b * HH))[c4] = o;
    }
}

// ---------------- K1: t = d_rep @ W_rel^T  (fp32 NT, 64x64x16; 0.6 GFLOP) ----------------
__global__ __launch_bounds__(256) void k_gemm_nt(const float* __restrict__ A,
                                                 const float* __restrict__ Bm,
                                                 float* __restrict__ C,
                                                 int N, int K) {
    __shared__ float As[64 * 20];
    __shared__ float Bs[64 * 20];
    int tid = threadIdx.x;
    int ty = tid >> 4, tx = tid & 15;
    int m0 = blockIdx.y * 64, n0 = blockIdx.x * 64;
    int lr = tid >> 2, lc = (tid & 3) * 4;
    float acc[4][4] = {};
    for (int kt = 0; kt < K; kt += 16) {
        *(float4*)(As + lr * 20 + lc) = *(const float4*)(A + (size_t)(m0 + lr) * K + kt + lc);
        *(float4*)(Bs + lr * 20 + lc) = *(const float4*)(Bm + (size_t)(n0 + lr) * K + kt + lc);
        __syncthreads();
        #pragma unroll
        for (int k = 0; k < 16; k += 2) {
            float2 ar[4], br[4];
            #pragma unroll
            for (int ii = 0; ii < 4; ++ii) ar[ii] = *(const float2*)(As + (ty + 16 * ii) * 20 + k);
            #pragma unroll
            for (int jj = 0; jj < 4; ++jj) br[jj] = *(const float2*)(Bs + (tx + 16 * jj) * 20 + k);
            #pragma unroll
            for (int ii = 0; ii < 4; ++ii)
                #pragma unroll
                for (int jj = 0; jj < 4; ++jj)
                    acc[ii][jj] = fmaf(ar[ii].y, br[jj].y, fmaf(ar[ii].x, br[jj].x, acc[ii][jj]));
        }
        __syncthreads();
    }
    #pragma unroll
    for (int ii = 0; ii < 4; ++ii)
        #pragma unroll
        for (int jj = 0; jj < 4; ++jj)
            C[(size_t)(m0 + ty + 16 * ii) * N + n0 + tx + 16 * jj] = acc[ii][jj];
}

// ---------------- K_splitw: W(K x N) -> Wt_h/Wt_l (N x K) bf16 split ----------------
__global__ __launch_bounds__(256) void k_splitw(const float* __restrict__ W,
                                                __bf16* __restrict__ th,
                                                __bf16* __restrict__ tl) {
    __shared__ float tile[32][33];
    int bn = blockIdx.x * 32, bk = blockIdx.y * 32;
    int tx = threadIdx.x & 31, ty = threadIdx.x >> 5;
    for (int r = ty; r < 32; r += 8)
        tile[r][tx] = W[(size_t)(bk + r) * HH + bn + tx];
    __syncthreads();
    for (int r = ty; r < 32; r += 8) {
        float v = tile[tx][r];
        __bf16 hv = (__bf16)v;
        size_t idx = (size_t)(bn + r) * HH + bk + tx;
        th[idx] = hv;
        tl[idx] = (__bf16)(v - (float)hv);
    }
}

// ---------------- K_split+contrel: split X chunk to bf16 hi/lo AND a[b,i]=X[b,i]·u[b]+b00 ----------------
__global__ __launch_bounds__(512) void k_split_contrel(const float* __restrict__ X,
                                                       const float* __restrict__ Wc,
                                                       const float* __restrict__ tmat,
                                                       const float* __restrict__ bmat,
                                                       __bf16* __restrict__ Xh,
                                                       __bf16* __restrict__ Xl,
                                                       float* __restrict__ avec,
                                                       int b_off) {
    __shared__ float4 u4[192];
    int lb = blockIdx.x, half = blockIdx.y;
    int b = b_off + lb;
    int tid = threadIdx.x, lane = tid & 63, w = tid >> 6;
    for (int c = tid; c < 192; c += 512) {
        float4 wc = ((const float4*)Wc)[c];
        float4 tm = ((const float4*)(tmat + (size_t)b * HH))[c];
        float4 o = {wc.x + tm.x, wc.y + tm.y, wc.z + tm.z, wc.w + tm.w};
        u4[c] = o;
    }
    __syncthreads();
    float b00 = bmat[0];
    const float4* xb = (const float4*)(X + (size_t)b * SS * HH);
    bf16x4* xh4 = (bf16x4*)(Xh + (size_t)lb * SS * HH);
    bf16x4* xl4 = (bf16x4*)(Xl + (size_t)lb * SS * HH);
    int rend = half * 50 + 50;
    for (int r = half * 50 + w; r < rend; r += 8) {
        float s = 0.f;
        #pragma unroll
        for (int cc = 0; cc < 3; ++cc) {
            int c = cc * 64 + lane;
            float4 v = xb[r * 192 + c];
            float4 uu = u4[c];
            s = fmaf(v.x, uu.x, fmaf(v.y, uu.y, fmaf(v.z, uu.z, fmaf(v.w, uu.w, s))));
            bf16x4 hv, lv;
            hv[0] = (__bf16)v.x; lv[0] = (__bf16)(v.x - (float)hv[0]);
            hv[1] = (__bf16)v.y; lv[1] = (__bf16)(v.y - (float)hv[1]);
            hv[2] = (__bf16)v.z; lv[2] = (__bf16)(v.z - (float)hv[2]);
            hv[3] = (__bf16)v.w; lv[3] = (__bf16)(v.w - (float)hv[3]);
            xh4[r * 192 + c] = hv;
            xl4[r * 192 + c] = lv;
        }
        #pragma unroll
        for (int off = 32; off > 0; off >>= 1) s += __shfl_down(s, off);
        if (lane == 0) avec[(size_t)b * SS + r] = s + b00;
    }
}

// ---------------- K3: GEMM1 MFMA 32x32x16  Y = X @ W  (NT, split-bf16, 128x128, BK=32) ----------------
// R9: single dispatch restored (R5 geometry: dbuf 64KB, 2 blocks/CU, XOR swizzle, XCD remap)
// + 2-sub-phase schedule (T3-lite): P1 {issue A-half(t+1); vmcnt(4) -> tile t fully landed
// (4 newest = A(t+1)); barrier; kh0 ds_read + 12 MFMA w/ setprio}; P2 {issue B-half(t+1),
// no wait; kh1 + 12 MFMA; barrier}. Loads span phases; vmcnt never drains to 0 in the loop.
__global__ __launch_bounds__(256) void k_gemm1_mfma(const __bf16* __restrict__ Ah_g,
                                                    const __bf16* __restrict__ Al_g,
                                                    const __bf16* __restrict__ Bh_g,
                                                    const __bf16* __restrict__ Bl_g,
                                                    __bf16* __restrict__ Yh,
                                                    __bf16* __restrict__ Yl) {
    __shared__ __align__(16) __bf16 lds[2 * 4 * 4096];   // 64 KB, 2 buffers
    const int tid = threadIdx.x;
    const int wave = tid >> 6, lane = tid & 63;
    const int wy = wave >> 1, wx = wave & 1;
    // m204-bijective XCD remap (grid 2400: q8=300, r8=0 -> tile = xcd*300 + idx)
    const int nwg = gridDim.x;
    const int lid = blockIdx.x;
    const int q8 = nwg >> 3, r8 = nwg & 7;
    const int xcd = lid & 7, sidx = lid >> 3;
    const int tile = (xcd < r8 ? xcd * (q8 + 1) : r8 * (q8 + 1) + (xcd - r8) * q8) + sidx;
    const size_t m0 = (size_t)(tile / 6) * 128;
    const int n0 = (tile % 6) * 128;

    const int srow = wave * 32 + (lane >> 2);
    const int scol = ((lane & 3) ^ ((lane >> 3) & 3)) * 8;   // pre-swizzled global source chunk
    const int lds_base = wave * 1024;

    const int arow = wy * 64 + (lane & 31);   // + t*32
    const int brow = wx * 64 + (lane & 31);
    const int sw = (lane >> 1) & 3;

    f32x16 acc[2][2] = {};

    auto stageA = [&](int buf, int kt) {       // 4 loads: A hi/lo
        __bf16* base = lds + buf * 16384;
        const size_t ga0 = (m0 + srow) * HH + kt + scol;
        const size_t ga1 = ga0 + (size_t)16 * HH;
        gld16(Ah_g + ga0, base + lds_base);
        gld16(Ah_g + ga1, base + lds_base + 512);
        gld16(Al_g + ga0, base + 4096 + lds_base);
        gld16(Al_g + ga1, base + 4096 + lds_base + 512);
    };
    auto stageB = [&](int buf, int kt) {       // 4 loads: B hi/lo
        __bf16* base = lds + buf * 16384;
        const size_t gb0 = (size_t)(n0 + srow) * HH + kt + scol;
        const size_t gb1 = gb0 + (size_t)16 * HH;
        gld16(Bh_g + gb0, base + 8192 + lds_base);
        gld16(Bh_g + gb1, base + 8192 + lds_base + 512);
        gld16(Bl_g + gb0, base + 12288 + lds_base);
        gld16(Bl_g + gb1, base + 12288 + lds_base + 512);
    };
    auto compute_kh = [&](int buf, int kh) {   // one K-half: 8 ds_read + 12 MFMA
        const __bf16* As_h = lds + buf * 16384;
        const __bf16* As_l = As_h + 4096;
        const __bf16* Bs_h = As_h + 8192;
        const __bf16* Bs_l = As_h + 12288;
        const int ko = (((kh << 1) + (lane >> 5)) ^ sw) << 3;
        bf16x8 fah[2], fal[2], fbh[2], fbl[2];
        #pragma unroll
        for (int t = 0; t < 2; ++t) {
            fah[t] = *(const bf16x8*)(As_h + (arow + t * 32) * 32 + ko);
            fal[t] = *(const bf16x8*)(As_l + (arow + t * 32) * 32 + ko);
            fbh[t] = *(const bf16x8*)(Bs_h + (brow + t * 32) * 32 + ko);
            fbl[t] = *(const bf16x8*)(Bs_l + (brow + t * 32) * 32 + ko);
        }
        __builtin_amdgcn_s_setprio(1);
        #pragma unroll
        for (int ti = 0; ti < 2; ++ti)
            #pragma unroll
            for (int tj = 0; tj < 2; ++tj) {
                acc[ti][tj] = __builtin_amdgcn_mfma_f32_32x32x16_bf16(fal[ti], fbh[tj], acc[ti][tj], 0, 0, 0);
                acc[ti][tj] = __builtin_amdgcn_mfma_f32_32x32x16_bf16(fah[ti], fbl[tj], acc[ti][tj], 0, 0, 0);
                acc[ti][tj] = __builtin_amdgcn_mfma_f32_32x32x16_bf16(fah[ti], fbh[tj], acc[ti][tj], 0, 0, 0);
            }
        __builtin_amdgcn_s_setprio(0);
    };

    stageA(0, 0);
    stageB(0, 0);
    int cur = 0;
    for (int i = 0; i < HH / 32; ++i) {
        const int nkt = (i + 1) * 32;
        // P1: issue next A-half, wait tile-i landed (4 newest = A(i+1)), sync, compute kh0
        if (nkt < HH) {
            stageA(cur ^ 1, nkt);
            asm volatile("s_waitcnt vmcnt(4)" ::: "memory");
        } else {
            asm volatile("s_waitcnt vmcnt(0)" ::: "memory");
        }
        __builtin_amdgcn_s_barrier();
        compute_kh(cur, 0);
        // P2: issue next B-half (no wait needed), compute kh1, end barrier (WAR fence)
        if (nkt < HH) stageB(cur ^ 1, nkt);
        compute_kh(cur, 1);
        __builtin_amdgcn_s_barrier();
        cur ^= 1;
    }

    // 32x32 C/D: col = lane&31, row = (reg&3) + 8*(reg>>2) + 4*(lane>>5)  [m74/m101]
    const int rbase = 4 * (lane >> 5);
    const int colb = lane & 31;
    #pragma unroll
    for (int ti = 0; ti < 2; ++ti) {
        #pragma unroll
        for (int tj = 0; tj < 2; ++tj) {
            int col = n0 + wx * 64 + tj * 32 + colb;
            #pragma unroll
            for (int r = 0; r < 16; ++r) {
                int row = wy * 64 + ti * 32 + (r & 3) + 8 * (r >> 2) + rbase;
                float v = acc[ti][tj][r];
                __bf16 hv = (__bf16)v;
                size_t idx = (m0 + row) * HH + col;
                Yh[idx] = hv;
                Yl[idx] = (__bf16)(v - (float)hv);
            }
        }
    }
}

// ---------------- K4: GEMM2 MFMA 32x32x16  q[b] = sigmoid(Y[b] @ X[b]^T + a[b,i]) ----------------
// One 128x128 block per batch. Same 2-sub-phase schedule as K3.
__global__ __launch_bounds__(256) void k_gemm2_mfma(const __bf16* __restrict__ Yh,
                                                    const __bf16* __restrict__ Yl,
                                                    const __bf16* __restrict__ Xh,
                                                    const __bf16* __restrict__ Xl,
                                                    const float* __restrict__ avec,
                                                    float* __restrict__ q, int b_off) {
    __shared__ __align__(16) __bf16 lds[2 * 4 * 4096];
    __shared__ float av_s[SS];
    const int bl = blockIdx.x;
    const int b = b_off + bl;
    const __bf16* Ah_g = Yh + (size_t)bl * SS * HH;
    const __bf16* Al_g = Yl + (size_t)bl * SS * HH;
    const __bf16* Bh_g = Xh + (size_t)bl * SS * HH;
    const __bf16* Bl_g = Xl + (size_t)bl * SS * HH;
    const int tid = threadIdx.x;
    const int wave = tid >> 6, lane = tid & 63;
    const int wy = wave >> 1, wx = wave & 1;
    if (tid < SS) av_s[tid] = avec[(size_t)b * SS + tid];

    const int srow_raw = wave * 32 + (lane >> 2);
    const int scol = ((lane & 3) ^ ((lane >> 3) & 3)) * 8;
    const int lds_base = wave * 1024;
    const int r0 = srow_raw < SS ? srow_raw : SS - 1;
    const int r1 = (srow_raw + 16) < SS ? (srow_raw + 16) : SS - 1;

    const int arow = wy * 64 + (lane & 31);
    const int brow = wx * 64 + (lane & 31);
    const int sw = (lane >> 1) & 3;

    f32x16 acc[2][2] = {};

    auto stageA = [&](int buf, int kt) {
        __bf16* base = lds + buf * 16384;
        const size_t ga0 = (size_t)r0 * HH + kt + scol;
        const size_t ga1 = (size_t)r1 * HH + kt + scol;
        gld16(Ah_g + ga0, base + lds_base);
        gld16(Ah_g + ga1, base + lds_base + 512);
        gld16(Al_g + ga0, base + 4096 + lds_base);
        gld16(Al_g + ga1, base + 4096 + lds_base + 512);
    };
    auto stageB = [&](int buf, int kt) {
        __bf16* base = lds + buf * 16384;
        const size_t ga0 = (size_t)r0 * HH + kt + scol;
        const size_t ga1 = (size_t)r1 * HH + kt + scol;
        gld16(Bh_g + ga0, base + 8192 + lds_base);
        gld16(Bh_g + ga1, base + 8192 + lds_base + 512);
        gld16(Bl_g + ga0, base + 12288 + lds_base);
        gld16(Bl_g + ga1, base + 12288 + lds_base + 512);
    };
    auto compute_kh = [&](int buf, int kh) {
        const __bf16* As_h = lds + buf * 16384;
        const __bf16* As_l = As_h + 4096;
        const __bf16* Bs_h = As_h + 8192;
        const __bf16* Bs_l = As_h + 12288;
        const int ko = (((kh << 1) + (lane >> 5)) ^ sw) << 3;
        bf16x8 fah[2], fal[2], fbh[2], fbl[2];
        #pragma unroll
        for (int t = 0; t < 2; ++t) {
            fah[t] = *(const bf16x8*)(As_h + (arow + t * 32) * 32 + ko);
            fal[t] = *(const bf16x8*)(As_l + (arow + t * 32) * 32 + ko);
            fbh[t] = *(const bf16x8*)(Bs_h + (brow + t * 32) * 32 + ko);
            fbl[t] = *(const bf16x8*)(Bs_l + (brow + t * 32) * 32 + ko);
        }
        __builtin_amdgcn_s_setprio(1);
        #pragma unroll
        for (int ti = 0; ti < 2; ++ti)
            #pragma unroll
            for (int tj = 0; tj < 2; ++tj) {
                acc[ti][tj] = __builtin_amdgcn_mfma_f32_32x32x16_bf16(fal[ti], fbh[tj], acc[ti][tj], 0, 0, 0);
                acc[ti][tj] = __builtin_amdgcn_mfma_f32_32x32x16_bf16(fah[ti], fbl[tj], acc[ti][tj], 0, 0, 0);
                acc[ti][tj] = __builtin_amdgcn_mfma_f32_32x32x16_bf16(fah[ti], fbh[tj], acc[ti][tj], 0, 0, 0);
            }
        __builtin_amdgcn_s_setprio(0);
    };

    stageA(0, 0);
    stageB(0, 0);
    int cur = 0;
    for (int i = 0; i < HH / 32; ++i) {
        const int nkt = (i + 1) * 32;
        if (nkt < HH) {
            stageA(cur ^ 1, nkt);
            asm volatile("s_waitcnt vmcnt(4)" ::: "memory");
        } else {
            asm volatile("s_waitcnt vmcnt(0)" ::: "memory");
        }
        __builtin_amdgcn_s_barrier();
        compute_kh(cur, 0);
        if (nkt < HH) stageB(cur ^ 1, nkt);
        compute_kh(cur, 1);
        __builtin_amdgcn_s_barrier();
        cur ^= 1;
    }

    float* qb = q + (size_t)b * SS * SS;
    const int rbase = 4 * (lane >> 5);
    const int colb = lane & 31;
    #pragma unroll
    for (int ti = 0; ti < 2; ++ti) {
        #pragma unroll
        for (int tj = 0; tj < 2; ++tj) {
            int j = wx * 64 + tj * 32 + colb;
            if (j >= SS) continue;
            #pragma unroll
            for (int r = 0; r < 16; ++r) {
                int i = wy * 64 + ti * 32 + (r & 3) + 8 * (r >> 2) + rbase;
                if (i >= SS) continue;
                float v = acc[ti][tj][r] + av_s[i];
                qb[(size_t)i * SS + j] = 1.0f / (1.0f + __expf(-v));
            }
        }
    }
}

// ---------------- K5: colsum + fixed-point solve, M held in registers ----------------
__global__ __launch_bounds__(128) void k_solve(const float* __restrict__ q,
                                               float* __restrict__ out) {
    __shared__ __align__(16) float m[SS * SS];
    __shared__ __align__(16) float csinv[SS];
    __shared__ __align__(16) float x0[SS], x1[SS];
    int b = blockIdx.x, tid = threadIdx.x;
    const float* qb = q + (size_t)b * SS * SS;
    for (int e4 = tid; e4 < SS * SS / 4; e4 += 128)
        *(float4*)(m + e4 * 4) = *(const float4*)(qb + (size_t)e4 * 4);
    __syncthreads();
    if (tid < SS) {
        float s = 0.f;
        for (int i = 0; i < SS; ++i) s += m[i * SS + tid];
        csinv[tid] = 0.8f / s;
        x0[tid] = 1.0f / SS;
    }
    __syncthreads();
    float4 mreg[25];
    if (tid < SS) {
        #pragma unroll
        for (int j4 = 0; j4 < 25; ++j4) {
            float4 mv = *(const float4*)(m + tid * SS + j4 * 4);
            float4 cv = *(const float4*)(csinv + j4 * 4);
            mreg[j4].x = mv.x * cv.x;
            mreg[j4].y = mv.y * cv.y;
            mreg[j4].z = mv.z * cv.z;
            mreg[j4].w = mv.w * cv.w;
        }
    } else {
        #pragma unroll
        for (int j4 = 0; j4 < 25; ++j4) mreg[j4] = float4{0, 0, 0, 0};
    }
    __syncthreads();
    #pragma unroll 1
    for (int it = 0; it < 56; ++it) {
        const float* xr = (it & 1) ? x1 : x0;
        float* xw = (it & 1) ? x0 : x1;
        if (tid < SS) {
            float sx = 0.f, sy = 0.f, sz = 0.f, sw = 0.f;
            #pragma unroll
            for (int j4 = 0; j4 < 25; ++j4) {
                float4 xv = *(const float4*)(xr + j4 * 4);
                sx = fmaf(mreg[j4].x, xv.x, sx);
                sy = fmaf(mreg[j4].y, xv.y, sy);
                sz = fmaf(mreg[j4].z, xv.z, sz);
                sw = fmaf(mreg[j4].w, xv.w, sw);
            }
            xw[tid] = 0.002f + ((sx + sy) + (sz + sw));
        }
        __syncthreads();
    }
    if (tid < SS) out[(size_t)b * SS + tid] = x0[tid];
}

extern "C" void kernel_launch(void* const* d_in, const int* in_sizes, int n_in,
                              void* d_out, int out_size, void* d_ws, size_t ws_size,
                              hipStream_t stream) {
    (void)in_sizes; (void)n_in; (void)out_size;
    const float* X    = (const float*)d_in[0];
    const float* Wc   = (const float*)d_in[2];
    const float* Wsim = (const float*)d_in[3];
    const float* Wrel = (const float*)d_in[4];
    const float* bmat = (const float*)d_in[5];
    float* out = (float*)d_out;

    char* ws = (char*)d_ws;
    size_t off = 0;
    float*  qbuf = (float*)(ws + off);  off += (size_t)BB * SS * SS * 4;
    float*  drep = (float*)(ws + off);  off += (size_t)BB * HH * 4;
    float*  tmat = (float*)(ws + off);  off += (size_t)BB * HH * 4;
    float*  avec = (float*)(ws + off);  off += (size_t)BB * SS * 4;
    __bf16* Wth  = (__bf16*)(ws + off); off += (size_t)HH * HH * 2;
    __bf16* Wtl  = (__bf16*)(ws + off); off += (size_t)HH * HH * 2;

    int CB = 512;
    while (CB > 128 && off + 4 * (size_t)CB * SS * HH * 2 > ws_size) CB >>= 1;
    size_t xsz = (size_t)CB * SS * HH * 2;
    __bf16* Xh = (__bf16*)(ws + off); off += xsz;
    __bf16* Xl = (__bf16*)(ws + off); off += xsz;
    __bf16* Yh = (__bf16*)(ws + off); off += xsz;
    __bf16* Yl = (__bf16*)(ws + off); off += xsz;

    k_drep<<<dim3(BB, 3), 256, 0, stream>>>(X, drep);
    k_gemm_nt<<<dim3(HH / 64, BB / 64), 256, 0, stream>>>(drep, Wrel, tmat, HH, HH);
    k_splitw<<<dim3(HH / 32, HH / 32), 256, 0, stream>>>(Wsim, Wth, Wtl);

    for (int c = 0; c < BB; c += CB) {
        k_split_contrel<<<dim3(CB, 2), 512, 0, stream>>>(X + (size_t)c * SS * HH, Wc, tmat, bmat, Xh, Xl, avec, c);
        k_gemm1_mfma<<<CB * SS / 128 * (HH / 128), 256, 0, stream>>>(Xh, Xl, Wth, Wtl, Yh, Yl);
        k_gemm2_mfma<<<CB, 256, 0, stream>>>(Yh, Yl, Xh, Xl, avec, qbuf, c);
    }
    k_solve<<<BB, 128, 0, stream>>>(qbuf, out);
}

// Round 10
// 704.981 us; speedup vs baseline: 1.0578x; 1.0018x over previous
//
#include <hip/hip_runtime.h>
#include <math.h>

#define BB 512
#define SS 100
#define HH 768

typedef __bf16 bf16x8 __attribute__((ext_vector_type(8)));
typedef __bf16 bf16x4 __attribute__((ext_vector_type(4)));
typedef float f32x4 __attribute__((ext_vector_type(4)));
typedef float f32x16 __attribute__((ext_vector_type(16)));

__device__ __forceinline__ void gld16(const void* g, void* l) {
    __builtin_amdgcn_global_load_lds((const __attribute__((address_space(1))) char*)g,
                                     (__attribute__((address_space(3))) char*)l, 16, 0, 0);
}

// ---------------- K0: d_rep[b,h] = mean_s X[b,s,h]  (coalesced float4 col-reduce) ----------------
__global__ __launch_bounds__(256) void k_drep(const float* __restrict__ X,
                                              float* __restrict__ drep) {
    int b = blockIdx.x, g = blockIdx.y;
    int lane = threadIdx.x & 63, w = threadIdx.x >> 6;
    const float4* xb = (const float4*)(X + (size_t)b * SS * HH);
    int c4 = g * 64 + lane;
    float4 s = {0.f, 0.f, 0.f, 0.f};
    for (int r = w; r < SS; r += 4) {
        float4 v = xb[r * 192 + c4];
        s.x += v.x; s.y += v.y; s.z += v.z; s.w += v.w;
    }
    __shared__ float4 red[4][64];
    red[w][lane] = s;
    __syncthreads();
    if (w == 0) {
        float4 a0 = red[0][lane], a1 = red[1][lane], a2 = red[2][lane], a3 = red[3][lane];
        float4 o;
        o.x = (a0.x + a1.x + a2.x + a3.x) * (1.0f / SS);
        o.y = (a0.y + a1.y + a2.y + a3.y) * (1.0f / SS);
        o.z = (a0.z + a1.z + a2.z + a3.z) * (1.0f / SS);
        o.w = (a0.w + a1.w + a2.w + a3.w) * (1.0f / SS);
        ((float4*)(drep + (size_t)b * HH))[c4] = o;
    }
}

// ---------------- K1: t = d_rep @ W_rel^T  (fp32 NT, 64x64x16; 0.6 GFLOP) ----------------
__global__ __launch_bounds__(256) void k_gemm_nt(const float* __restrict__ A,
                                                 const float* __restrict__ Bm,
                                                 float* __restrict__ C,
                                                 int N, int K) {
    __shared__ float As[64 * 20];
    __shared__ float Bs[64 * 20];
    int tid = threadIdx.x;
    int ty = tid >> 4, tx = tid & 15;
    int m0 = blockIdx.y * 64, n0 = blockIdx.x * 64;
    int lr = tid >> 2, lc = (tid & 3) * 4;
    float acc[4][4] = {};
    for (int kt = 0; kt < K; kt += 16) {
        *(float4*)(As + lr * 20 + lc) = *(const float4*)(A + (size_t)(m0 + lr) * K + kt + lc);
        *(float4*)(Bs + lr * 20 + lc) = *(const float4*)(Bm + (size_t)(n0 + lr) * K + kt + lc);
        __syncthreads();
        #pragma unroll
        for (int k = 0; k < 16; k += 2) {
            float2 ar[4], br[4];
            #pragma unroll
            for (int ii = 0; ii < 4; ++ii) ar[ii] = *(const float2*)(As + (ty + 16 * ii) * 20 + k);
            #pragma unroll
            for (int jj = 0; jj < 4; ++jj) br[jj] = *(const float2*)(Bs + (tx + 16 * jj) * 20 + k);
            #pragma unroll
            for (int ii = 0; ii < 4; ++ii)
                #pragma unroll
                for (int jj = 0; jj < 4; ++jj)
                    acc[ii][jj] = fmaf(ar[ii].y, br[jj].y, fmaf(ar[ii].x, br[jj].x, acc[ii][jj]));
        }
        __syncthreads();
    }
    #pragma unroll
    for (int ii = 0; ii < 4; ++ii)
        #pragma unroll
        for (int jj = 0; jj < 4; ++jj)
            C[(size_t)(m0 + ty + 16 * ii) * N + n0 + tx + 16 * jj] = acc[ii][jj];
}

// ---------------- K_splitw: W(K x N) -> Wt_h/Wt_l (N x K) bf16 split ----------------
__global__ __launch_bounds__(256) void k_splitw(const float* __restrict__ W,
                                                __bf16* __restrict__ th,
                                                __bf16* __restrict__ tl) {
    __shared__ float tile[32][33];
    int bn = blockIdx.x * 32, bk = blockIdx.y * 32;
    int tx = threadIdx.x & 31, ty = threadIdx.x >> 5;
    for (int r = ty; r < 32; r += 8)
        tile[r][tx] = W[(size_t)(bk + r) * HH + bn + tx];
    __syncthreads();
    for (int r = ty; r < 32; r += 8) {
        float v = tile[tx][r];
        __bf16 hv = (__bf16)v;
        size_t idx = (size_t)(bn + r) * HH + bk + tx;
        th[idx] = hv;
        tl[idx] = (__bf16)(v - (float)hv);
    }
}

// ---------------- K_split+contrel: split X chunk to bf16 hi/lo AND a[b,i]=X[b,i]·u[b]+b00 ----------------
__global__ __launch_bounds__(512) void k_split_contrel(const float* __restrict__ X,
                                                       const float* __restrict__ Wc,
                                                       const float* __restrict__ tmat,
                                                       const float* __restrict__ bmat,
                                                       __bf16* __restrict__ Xh,
                                                       __bf16* __restrict__ Xl,
                                                       float* __restrict__ avec,
                                                       int b_off) {
    __shared__ float4 u4[192];
    int lb = blockIdx.x, half = blockIdx.y;
    int b = b_off + lb;
    int tid = threadIdx.x, lane = tid & 63, w = tid >> 6;
    for (int c = tid; c < 192; c += 512) {
        float4 wc = ((const float4*)Wc)[c];
        float4 tm = ((const float4*)(tmat + (size_t)b * HH))[c];
        float4 o = {wc.x + tm.x, wc.y + tm.y, wc.z + tm.z, wc.w + tm.w};
        u4[c] = o;
    }
    __syncthreads();
    float b00 = bmat[0];
    const float4* xb = (const float4*)(X + (size_t)b * SS * HH);
    bf16x4* xh4 = (bf16x4*)(Xh + (size_t)lb * SS * HH);
    bf16x4* xl4 = (bf16x4*)(Xl + (size_t)lb * SS * HH);
    int rend = half * 50 + 50;
    for (int r = half * 50 + w; r < rend; r += 8) {
        float s = 0.f;
        #pragma unroll
        for (int cc = 0; cc < 3; ++cc) {
            int c = cc * 64 + lane;
            float4 v = xb[r * 192 + c];
            float4 uu = u4[c];
            s = fmaf(v.x, uu.x, fmaf(v.y, uu.y, fmaf(v.z, uu.z, fmaf(v.w, uu.w, s))));
            bf16x4 hv, lv;
            hv[0] = (__bf16)v.x; lv[0] = (__bf16)(v.x - (float)hv[0]);
            hv[1] = (__bf16)v.y; lv[1] = (__bf16)(v.y - (float)hv[1]);
            hv[2] = (__bf16)v.z; lv[2] = (__bf16)(v.z - (float)hv[2]);
            hv[3] = (__bf16)v.w; lv[3] = (__bf16)(v.w - (float)hv[3]);
            xh4[r * 192 + c] = hv;
            xl4[r * 192 + c] = lv;
        }
        #pragma unroll
        for (int off = 32; off > 0; off >>= 1) s += __shfl_down(s, off);
        if (lane == 0) avec[(size_t)b * SS + r] = s + b00;
    }
}

// ---------------- K3: GEMM1 MFMA 32x32x16  Y = X @ W  (NT, split-bf16) ----------------
// R10: m201-style fine-phase schedule on R6's verified 256x256 geometry (512 thr, 8 waves of
// 128x64, 128 KB LDS dbuf, XOR swizzle, bijective XCD remap). Per K-step (BK=32): 4 phases,
// each {ds_read sub-quadrant || issue 2 gld16(t+1) -> s_barrier -> setprio(1)+12 MFMA+setprio(0)
// -> s_barrier}. vmcnt(2) ONCE per K-step at phase 0 (the 2 just-issued t+1 loads are the only
// ones left in flight -> tile t confirmed). Loads span phases; never drained to 0 in the loop.
__global__ __launch_bounds__(512) void k_gemm1_mfma(const __bf16* __restrict__ Ah_g,
                                                    const __bf16* __restrict__ Al_g,
                                                    const __bf16* __restrict__ Bh_g,
                                                    const __bf16* __restrict__ Bl_g,
                                                    __bf16* __restrict__ Yh,
                                                    __bf16* __restrict__ Yl) {
    __shared__ __align__(16) __bf16 lds[2 * 32768];   // 128 KB, 2 buffers
    const int tid = threadIdx.x;
    const int wave = tid >> 6, lane = tid & 63;
    const int wy = wave >> 2, wx = wave & 3;           // 2 x 4 wave grid, 128x64 per wave
    // m204-bijective XCD remap
    const int nwg = gridDim.x;
    const int lid = blockIdx.x;
    const int q8 = nwg >> 3, r8 = nwg & 7;
    const int xcd = lid & 7, sidx = lid >> 3;
    const int tile = (xcd < r8 ? xcd * (q8 + 1) : r8 * (q8 + 1) + (xcd - r8) * q8) + sidx;
    const size_t m0 = (size_t)(tile / 3) * 256;
    const int n0 = (tile % 3) * 256;

    const int srow = tid >> 2;                          // 0..127 (+128 for second gld16)
    const int scol = ((lane & 3) ^ ((lane >> 3) & 3)) * 8;
    const int wbase = wave * 512;

    const int arow = wy * 128 + (lane & 31);            // + ti*32
    const int brow = wx * 64 + (lane & 31);             // + tj*32
    const int sw = (lane >> 1) & 3;

    f32x16 acc[4][2] = {};

    // piece-pair p: 0 = Ah, 1 = Al, 2 = Bh, 3 = Bl (2 gld16 each)
    auto stage_pair = [&](int buf, int kt, int p) {
        __bf16* base = lds + buf * 32768;
        if (p == 0) {
            const size_t ga0 = (m0 + srow) * HH + kt + scol;
            gld16(Ah_g + ga0, base + wbase);
            gld16(Ah_g + ga0 + (size_t)128 * HH, base + 4096 + wbase);
        } else if (p == 1) {
            const size_t ga0 = (m0 + srow) * HH + kt + scol;
            gld16(Al_g + ga0, base + 8192 + wbase);
            gld16(Al_g + ga0 + (size_t)128 * HH, base + 12288 + wbase);
        } else if (p == 2) {
            const size_t gb0 = (size_t)(n0 + srow) * HH + kt + scol;
            gld16(Bh_g + gb0, base + 16384 + wbase);
            gld16(Bh_g + gb0 + (size_t)128 * HH, base + 20480 + wbase);
        } else {
            const size_t gb0 = (size_t)(n0 + srow) * HH + kt + scol;
            gld16(Bl_g + gb0, base + 24576 + wbase);
            gld16(Bl_g + gb0 + (size_t)128 * HH, base + 28672 + wbase);
        }
    };

    #pragma unroll
    for (int p = 0; p < 4; ++p) stage_pair(0, 0, p);    // prologue: tile 0, 8 loads in flight

    int cur = 0;
    for (int t = 0; t < HH / 32; ++t) {
        const int nkt = (t + 1) * 32;
        const bool pf = nkt < HH;
        const __bf16* Ah_s = lds + cur * 32768;
        const __bf16* Al_s = Ah_s + 8192;
        const __bf16* Bh_s = Ah_s + 16384;
        const __bf16* Bl_s = Ah_s + 24576;
        #pragma unroll
        for (int kh = 0; kh < 2; ++kh) {
            const int ko = (((kh << 1) + (lane >> 5)) ^ sw) << 3;
            bf16x8 fbh[2], fbl[2];                      // live across the kh's two phases
            #pragma unroll
            for (int half = 0; half < 2; ++half) {
                const int ph = kh * 2 + half;
                bf16x8 fah2[2], fal2[2];
                if (ph == 0) {
                    // issue pair 0 of t+1, then confirm tile t (only the 2 new loads may remain)
                    if (pf) {
                        stage_pair(cur ^ 1, nkt, 0);
                        asm volatile("s_waitcnt vmcnt(2)" ::: "memory");
                    } else {
                        asm volatile("s_waitcnt vmcnt(0)" ::: "memory");
                    }
                    __builtin_amdgcn_s_barrier();       // all waves' tile-t staging visible
                    #pragma unroll
                    for (int t2 = 0; t2 < 2; ++t2) {
                        fbh[t2] = *(const bf16x8*)(Bh_s + (brow + t2 * 32) * 32 + ko);
                        fbl[t2] = *(const bf16x8*)(Bl_s + (brow + t2 * 32) * 32 + ko);
                        fah2[t2] = *(const bf16x8*)(Ah_s + (arow + t2 * 32) * 32 + ko);
                        fal2[t2] = *(const bf16x8*)(Al_s + (arow + t2 * 32) * 32 + ko);
                    }
                } else {
                    // reads first (buf confirmed at ph0) so ds latency overlaps the barrier
                    if (half == 0) {
                        #pragma unroll
                        for (int t2 = 0; t2 < 2; ++t2) {
                            fbh[t2] = *(const bf16x8*)(Bh_s + (brow + t2 * 32) * 32 + ko);
                            fbl[t2] = *(const bf16x8*)(Bl_s + (brow + t2 * 32) * 32 + ko);
                            fah2[t2] = *(const bf16x8*)(Ah_s + (arow + t2 * 32) * 32 + ko);
                            fal2[t2] = *(const bf16x8*)(Al_s + (arow + t2 * 32) * 32 + ko);
                        }
                    } else {
                        #pragma unroll
                        for (int t2 = 0; t2 < 2; ++t2) {
                            fah2[t2] = *(const bf16x8*)(Ah_s + (arow + (2 + t2) * 32) * 32 + ko);
                            fal2[t2] = *(const bf16x8*)(Al_s + (arow + (2 + t2) * 32) * 32 + ko);
                        }
                    }
                    if (pf) stage_pair(cur ^ 1, nkt, ph);
                    __builtin_amdgcn_s_barrier();       // phase-align the 8 waves
                }
                __builtin_amdgcn_s_setprio(1);
                #pragma unroll
                for (int tl = 0; tl < 2; ++tl) {
                    const int ti = half * 2 + tl;
                    #pragma unroll
                    for (int tj = 0; tj < 2; ++tj) {
                        acc[ti][tj] = __builtin_amdgcn_mfma_f32_32x32x16_bf16(fal2[tl], fbh[tj], acc[ti][tj], 0, 0, 0);
                        acc[ti][tj] = __builtin_amdgcn_mfma_f32_32x32x16_bf16(fah2[tl], fbl[tj], acc[ti][tj], 0, 0, 0);
                        acc[ti][tj] = __builtin_amdgcn_mfma_f32_32x32x16_bf16(fah2[tl], fbh[tj], acc[ti][tj], 0, 0, 0);
                    }
                }
                __builtin_amdgcn_s_setprio(0);
                __builtin_amdgcn_s_barrier();           // close phase window
            }
        }
        cur ^= 1;
    }

    // 32x32 C/D: col = lane&31, row = (reg&3) + 8*(reg>>2) + 4*(lane>>5)  [m74/m101]
    const int rbase = 4 * (lane >> 5);
    const int colb = lane & 31;
    #pragma unroll
    for (int ti = 0; ti < 4; ++ti) {
        #pragma unroll
        for (int tj = 0; tj < 2; ++tj) {
            int col = n0 + wx * 64 + tj * 32 + colb;
            #pragma unroll
            for (int r = 0; r < 16; ++r) {
                int row = wy * 128 + ti * 32 + (r & 3) + 8 * (r >> 2) + rbase;
                float v = acc[ti][tj][r];
                __bf16 hv = (__bf16)v;
                size_t idx = (m0 + row) * HH + col;
                Yh[idx] = hv;
                Yl[idx] = (__bf16)(v - (float)hv);
            }
        }
    }
}

// ---------------- K4: GEMM2 MFMA 32x32x16  q[b] = sigmoid(Y[b] @ X[b]^T + a[b,i]) ----------------
// One 128x128 block per batch. R9's 2-sub-phase schedule (kept).
__global__ __launch_bounds__(256) void k_gemm2_mfma(const __bf16* __restrict__ Yh,
                                                    const __bf16* __restrict__ Yl,
                                                    const __bf16* __restrict__ Xh,
                                                    const __bf16* __restrict__ Xl,
                                                    const float* __restrict__ avec,
                                                    float* __restrict__ q, int b_off) {
    __shared__ __align__(16) __bf16 lds[2 * 4 * 4096];
    __shared__ float av_s[SS];
    const int bl = blockIdx.x;
    const int b = b_off + bl;
    const __bf16* Ah_g = Yh + (size_t)bl * SS * HH;
    const __bf16* Al_g = Yl + (size_t)bl * SS * HH;
    const __bf16* Bh_g = Xh + (size_t)bl * SS * HH;
    const __bf16* Bl_g = Xl + (size_t)bl * SS * HH;
    const int tid = threadIdx.x;
    const int wave = tid >> 6, lane = tid & 63;
    const int wy = wave >> 1, wx = wave & 1;
    if (tid < SS) av_s[tid] = avec[(size_t)b * SS + tid];

    const int srow_raw = wave * 32 + (lane >> 2);
    const int scol = ((lane & 3) ^ ((lane >> 3) & 3)) * 8;
    const int lds_base = wave * 1024;
    const int r0 = srow_raw < SS ? srow_raw : SS - 1;
    const int r1 = (srow_raw + 16) < SS ? (srow_raw + 16) : SS - 1;

    const int arow = wy * 64 + (lane & 31);
    const int brow = wx * 64 + (lane & 31);
    const int sw = (lane >> 1) & 3;

    f32x16 acc[2][2] = {};

    auto stageA = [&](int buf, int kt) {
        __bf16* base = lds + buf * 16384;
        const size_t ga0 = (size_t)r0 * HH + kt + scol;
        const size_t ga1 = (size_t)r1 * HH + kt + scol;
        gld16(Ah_g + ga0, base + lds_base);
        gld16(Ah_g + ga1, base + lds_base + 512);
        gld16(Al_g + ga0, base + 4096 + lds_base);
        gld16(Al_g + ga1, base + 4096 + lds_base + 512);
    };
    auto stageB = [&](int buf, int kt) {
        __bf16* base = lds + buf * 16384;
        const size_t ga0 = (size_t)r0 * HH + kt + scol;
        const size_t ga1 = (size_t)r1 * HH + kt + scol;
        gld16(Bh_g + ga0, base + 8192 + lds_base);
        gld16(Bh_g + ga1, base + 8192 + lds_base + 512);
        gld16(Bl_g + ga0, base + 12288 + lds_base);
        gld16(Bl_g + ga1, base + 12288 + lds_base + 512);
    };
    auto compute_kh = [&](int buf, int kh) {
        const __bf16* As_h = lds + buf * 16384;
        const __bf16* As_l = As_h + 4096;
        const __bf16* Bs_h = As_h + 8192;
        const __bf16* Bs_l = As_h + 12288;
        const int ko = (((kh << 1) + (lane >> 5)) ^ sw) << 3;
        bf16x8 fah[2], fal[2], fbh[2], fbl[2];
        #pragma unroll
        for (int t = 0; t < 2; ++t) {
            fah[t] = *(const bf16x8*)(As_h + (arow + t * 32) * 32 + ko);
            fal[t] = *(const bf16x8*)(As_l + (arow + t * 32) * 32 + ko);
            fbh[t] = *(const bf16x8*)(Bs_h + (brow + t * 32) * 32 + ko);
            fbl[t] = *(const bf16x8*)(Bs_l + (brow + t * 32) * 32 + ko);
        }
        __builtin_amdgcn_s_setprio(1);
        #pragma unroll
        for (int ti = 0; ti < 2; ++ti)
            #pragma unroll
            for (int tj = 0; tj < 2; ++tj) {
                acc[ti][tj] = __builtin_amdgcn_mfma_f32_32x32x16_bf16(fal[ti], fbh[tj], acc[ti][tj], 0, 0, 0);
                acc[ti][tj] = __builtin_amdgcn_mfma_f32_32x32x16_bf16(fah[ti], fbl[tj], acc[ti][tj], 0, 0, 0);
                acc[ti][tj] = __builtin_amdgcn_mfma_f32_32x32x16_bf16(fah[ti], fbh[tj], acc[ti][tj], 0, 0, 0);
            }
        __builtin_amdgcn_s_setprio(0);
    };

    stageA(0, 0);
    stageB(0, 0);
    int cur = 0;
    for (int i = 0; i < HH / 32; ++i) {
        const int nkt = (i + 1) * 32;
        if (nkt < HH) {
            stageA(cur ^ 1, nkt);
            asm volatile("s_waitcnt vmcnt(4)" ::: "memory");
        } else {
            asm volatile("s_waitcnt vmcnt(0)" ::: "memory");
        }
        __builtin_amdgcn_s_barrier();
        compute_kh(cur, 0);
        if (nkt < HH) stageB(cur ^ 1, nkt);
        compute_kh(cur, 1);
        __builtin_amdgcn_s_barrier();
        cur ^= 1;
    }

    float* qb = q + (size_t)b * SS * SS;
    const int rbase = 4 * (lane >> 5);
    const int colb = lane & 31;
    #pragma unroll
    for (int ti = 0; ti < 2; ++ti) {
        #pragma unroll
        for (int tj = 0; tj < 2; ++tj) {
            int j = wx * 64 + tj * 32 + colb;
            if (j >= SS) continue;
            #pragma unroll
            for (int r = 0; r < 16; ++r) {
                int i = wy * 64 + ti * 32 + (r & 3) + 8 * (r >> 2) + rbase;
                if (i >= SS) continue;
                float v = acc[ti][tj][r] + av_s[i];
                qb[(size_t)i * SS + j] = 1.0f / (1.0f + __expf(-v));
            }
        }
    }
}

// ---------------- K5: colsum + fixed-point solve, M held in registers ----------------
__global__ __launch_bounds__(128) void k_solve(const float* __restrict__ q,
                                               float* __restrict__ out) {
    __shared__ __align__(16) float m[SS * SS];
    __shared__ __align__(16) float csinv[SS];
    __shared__ __align__(16) float x0[SS], x1[SS];
    int b = blockIdx.x, tid = threadIdx.x;
    const float* qb = q + (size_t)b * SS * SS;
    for (int e4 = tid; e4 < SS * SS / 4; e4 += 128)
        *(float4*)(m + e4 * 4) = *(const float4*)(qb + (size_t)e4 * 4);
    __syncthreads();
    if (tid < SS) {
        float s = 0.f;
        for (int i = 0; i < SS; ++i) s += m[i * SS + tid];
        csinv[tid] = 0.8f / s;
        x0[tid] = 1.0f / SS;
    }
    __syncthreads();
    float4 mreg[25];
    if (tid < SS) {
        #pragma unroll
        for (int j4 = 0; j4 < 25; ++j4) {
            float4 mv = *(const float4*)(m + tid * SS + j4 * 4);
            float4 cv = *(const float4*)(csinv + j4 * 4);
            mreg[j4].x = mv.x * cv.x;
            mreg[j4].y = mv.y * cv.y;
            mreg[j4].z = mv.z * cv.z;
            mreg[j4].w = mv.w * cv.w;
        }
    } else {
        #pragma unroll
        for (int j4 = 0; j4 < 25; ++j4) mreg[j4] = float4{0, 0, 0, 0};
    }
    __syncthreads();
    #pragma unroll 1
    for (int it = 0; it < 56; ++it) {
        const float* xr = (it & 1) ? x1 : x0;
        float* xw = (it & 1) ? x0 : x1;
        if (tid < SS) {
            float sx = 0.f, sy = 0.f, sz = 0.f, sw = 0.f;
            #pragma unroll
            for (int j4 = 0; j4 < 25; ++j4) {
                float4 xv = *(const float4*)(xr + j4 * 4);
                sx = fmaf(mreg[j4].x, xv.x, sx);
                sy = fmaf(mreg[j4].y, xv.y, sy);
                sz = fmaf(mreg[j4].z, xv.z, sz);
                sw = fmaf(mreg[j4].w, xv.w, sw);
            }
            xw[tid] = 0.002f + ((sx + sy) + (sz + sw));
        }
        __syncthreads();
    }
    if (tid < SS) out[(size_t)b * SS + tid] = x0[tid];
}

extern "C" void kernel_launch(void* const* d_in, const int* in_sizes, int n_in,
                              void* d_out, int out_size, void* d_ws, size_t ws_size,
                              hipStream_t stream) {
    (void)in_sizes; (void)n_in; (void)out_size;
    const float* X    = (const float*)d_in[0];
    const float* Wc   = (const float*)d_in[2];
    const float* Wsim = (const float*)d_in[3];
    const float* Wrel = (const float*)d_in[4];
    const float* bmat = (const float*)d_in[5];
    float* out = (float*)d_out;

    char* ws = (char*)d_ws;
    size_t off = 0;
    float*  qbuf = (float*)(ws + off);  off += (size_t)BB * SS * SS * 4;
    float*  drep = (float*)(ws + off);  off += (size_t)BB * HH * 4;
    float*  tmat = (float*)(ws + off);  off += (size_t)BB * HH * 4;
    float*  avec = (float*)(ws + off);  off += (size_t)BB * SS * 4;
    __bf16* Wth  = (__bf16*)(ws + off); off += (size_t)HH * HH * 2;
    __bf16* Wtl  = (__bf16*)(ws + off); off += (size_t)HH * HH * 2;

    int CB = 512;
    while (CB > 128 && off + 4 * (size_t)CB * SS * HH * 2 > ws_size) CB >>= 1;
    size_t xsz = (size_t)CB * SS * HH * 2;
    __bf16* Xh = (__bf16*)(ws + off); off += xsz;
    __bf16* Xl = (__bf16*)(ws + off); off += xsz;
    __bf16* Yh = (__bf16*)(ws + off); off += xsz;
    __bf16* Yl = (__bf16*)(ws + off); off += xsz;

    k_drep<<<dim3(BB, 3), 256, 0, stream>>>(X, drep);
    k_gemm_nt<<<dim3(HH / 64, BB / 64), 256, 0, stream>>>(drep, Wrel, tmat, HH, HH);
    k_splitw<<<dim3(HH / 32, HH / 32), 256, 0, stream>>>(Wsim, Wth, Wtl);

    for (int c = 0; c < BB; c += CB) {
        k_split_contrel<<<dim3(CB, 2), 512, 0, stream>>>(X + (size_t)c * SS * HH, Wc, tmat, bmat, Xh, Xl, avec, c);
        int nblk1 = (CB * SS / 256) * (HH / 256);   // 256x256 tiles -> 600 blocks
        k_gemm1_mfma<<<nblk1, 512, 0, stream>>>(Xh, Xl, Wth, Wtl, Yh, Yl);
        k_gemm2_mfma<<<CB, 256, 0, stream>>>(Yh, Yl, Xh, Xl, avec, qbuf, c);
    }
    k_solve<<<BB, 128, 0, stream>>>(qbuf, out);
}